// Round 1
// baseline (1085.690 us; speedup 1.0000x reference)
//
#include <hip/hip_runtime.h>

// ---------------------------------------------------------------------------
// GNNLoss: fp32 correctness-first implementation.
// N=2048, C=512, D=128, K_POOL=1024, NUM_HOP=2, POOL_HOP=1, T=0.07, NEG=-10.
// ---------------------------------------------------------------------------

#define TINV (1.0f / 0.07f)
#define NEGF (-10.0f)

// ---------------- generic 64x64 tiled fp32 GEMM ----------------------------
// C[M,N] = A[M,K] @ op(B) (+ bias | += C)
// BT=false: B is [K,N] row-major (ldb = row stride)
// BT=true : B is [N,K] row-major -> computes A @ B^T (gram style)
// MODE: 0 = store, 1 = store + bias[j], 2 = accumulate into C
// grid = (N/64, M/64), block = 256. Requires M,N %64==0, K%16==0, lda/ldb %4==0.
template<bool BT, int MODE>
__launch_bounds__(256)
__global__ void gemm64(const float* __restrict__ A, int lda,
                       const float* __restrict__ B, int ldb,
                       const float* __restrict__ bias,
                       float* __restrict__ C, int ldc, int K)
{
    __shared__ float As[16][68];
    __shared__ float Bs[16][68];
    const int tid = threadIdx.x;
    const int tx = tid & 15;
    const int ty = tid >> 4;
    const int i0 = blockIdx.y * 64;
    const int j0 = blockIdx.x * 64;
    const int lr = tid >> 2;        // 0..63
    const int lc = (tid & 3) * 4;   // 0,4,8,12
    float acc[4][4] = {};

    for (int k0 = 0; k0 < K; k0 += 16) {
        {
            float4 av = *(const float4*)(A + (size_t)(i0 + lr) * lda + (k0 + lc));
            As[lc + 0][lr] = av.x; As[lc + 1][lr] = av.y;
            As[lc + 2][lr] = av.z; As[lc + 3][lr] = av.w;
        }
        if (BT) {
            float4 bv = *(const float4*)(B + (size_t)(j0 + lr) * ldb + (k0 + lc));
            Bs[lc + 0][lr] = bv.x; Bs[lc + 1][lr] = bv.y;
            Bs[lc + 2][lr] = bv.z; Bs[lc + 3][lr] = bv.w;
        } else {
            const int n = tid & 63;
            const int kb = tid >> 6;   // 0..3
#pragma unroll
            for (int it = 0; it < 4; ++it)
                Bs[kb * 4 + it][n] = B[(size_t)(k0 + kb * 4 + it) * ldb + (j0 + n)];
        }
        __syncthreads();
#pragma unroll
        for (int kk = 0; kk < 16; ++kk) {
            float a[4], b[4];
#pragma unroll
            for (int u = 0; u < 4; ++u) a[u] = As[kk][ty * 4 + u];
#pragma unroll
            for (int v = 0; v < 4; ++v) b[v] = Bs[kk][tx * 4 + v];
#pragma unroll
            for (int u = 0; u < 4; ++u)
#pragma unroll
                for (int v = 0; v < 4; ++v)
                    acc[u][v] = fmaf(a[u], b[v], acc[u][v]);
        }
        __syncthreads();
    }

#pragma unroll
    for (int u = 0; u < 4; ++u) {
        const size_t ri = (size_t)(i0 + ty * 4 + u) * ldc + j0 + tx * 4;
#pragma unroll
        for (int v = 0; v < 4; ++v) {
            float val = acc[u][v];
            if (MODE == 1) val += bias[j0 + tx * 4 + v];
            if (MODE == 2) val += C[ri + v];
            C[ri + v] = val;
        }
    }
}

// ---------------- row l2 normalize (D=128), in place -----------------------
__global__ void l2norm_rows(float* __restrict__ X)
{
    const int row = blockIdx.x;
    const int tid = threadIdx.x;                 // 128 threads
    float v = X[(size_t)row * 128 + tid];
    __shared__ float red[128];
    red[tid] = v * v;
    __syncthreads();
    for (int s = 64; s > 0; s >>= 1) {
        if (tid < s) red[tid] += red[tid + s];
        __syncthreads();
    }
    X[(size_t)row * 128 + tid] = v * (1.0f / sqrtf(red[0]));
}

// ------------- threshold gram -> A(0/1), pack bits, deg -> dinv ------------
// block per row (2048 blocks, 256 threads). G overwritten with 0/1 A.
__global__ void threshold_pack(float* __restrict__ G,
                               unsigned long long* __restrict__ bits,
                               float* __restrict__ dinv)
{
    const int row = blockIdx.x;
    const int tid = threadIdx.x;
    const int lane = tid & 63;
    const int wave = tid >> 6;                   // 0..3
    int total = 0;
    for (int c = 0; c < 8; ++c) {
        const int chunk = wave * 8 + c;          // 0..31
        const int j = chunk * 64 + lane;
        float g = G[(size_t)row * 2048 + j];
        bool a = (j == row) ? true : (g > 0.0f); // TH=0, diag forced 1
        unsigned long long m = __ballot(a);
        G[(size_t)row * 2048 + j] = a ? 1.0f : 0.0f;
        if (lane == 0) bits[(size_t)row * 32 + chunk] = m;
        total += __popcll(m);
    }
    __shared__ int wred[4];
    if (lane == 0) wred[wave] = total;
    __syncthreads();
    if (tid == 0) {
        float deg = (float)(wred[0] + wred[1] + wred[2] + wred[3]);
        dinv[row] = 1.0f / sqrtf(deg);           // deg >= 1 (self loop)
    }
}

// ------------- A(0/1) -> An = A * dinv_i * dinv_j, in place ----------------
__global__ void scale_adj(float* __restrict__ A, const float* __restrict__ dinv,
                          int logn)
{
    const size_t idx = (size_t)blockIdx.x * 256 + threadIdx.x;
    const int i = (int)(idx >> logn);
    const int j = (int)(idx & ((1u << logn) - 1));
    float a = A[idx];
    A[idx] = (a != 0.0f) ? dinv[i] * dinv[j] : 0.0f;
}

// ------------- NCE row term: mean_i (LSE_i - pos_i/T) ----------------------
// block per row, 256 threads. logits = {pos, row w/ diag->-10} / T.
__global__ void nce_rows(const float* __restrict__ G, int n, float invN,
                         float* __restrict__ out)
{
    const int row = blockIdx.x;
    const int tid = threadIdx.x;
    const float pos = G[(size_t)row * n + row];
    float m = pos;
    for (int j = tid; j < n; j += 256) {
        float g = (j == row) ? NEGF : G[(size_t)row * n + j];
        m = fmaxf(m, g);
    }
    __shared__ float red[256];
    red[tid] = m;
    __syncthreads();
    for (int s = 128; s > 0; s >>= 1) {
        if (tid < s) red[tid] = fmaxf(red[tid], red[tid + s]);
        __syncthreads();
    }
    m = red[0];
    __syncthreads();
    float ssum = (tid == 0) ? expf((pos - m) * TINV) : 0.0f;
    for (int j = tid; j < n; j += 256) {
        float g = (j == row) ? NEGF : G[(size_t)row * n + j];
        ssum += expf((g - m) * TINV);
    }
    red[tid] = ssum;
    __syncthreads();
    for (int s = 128; s > 0; s >>= 1) {
        if (tid < s) red[tid] += red[tid + s];
        __syncthreads();
    }
    if (tid == 0)
        atomicAdd(out, (logf(red[0]) + (m - pos) * TINV) * invN);
}

// ------------- pooling score: sigmoid(f_gt @ W_pool + b) -------------------
__global__ void pool_score(const float* __restrict__ f,
                           const float* __restrict__ Wp,
                           const float* __restrict__ bp,
                           float* __restrict__ scores)
{
    const int row = blockIdx.x;
    const int tid = threadIdx.x;                 // 128
    float v = f[(size_t)row * 128 + tid] * Wp[tid];
    __shared__ float red[128];
    red[tid] = v;
    __syncthreads();
    for (int s = 64; s > 0; s >>= 1) {
        if (tid < s) red[tid] += red[tid + s];
        __syncthreads();
    }
    if (tid == 0) scores[row] = 1.0f / (1.0f + expf(-(red[0] + bp[0])));
}

// ------------- top-1024 of 2048: single-block bitonic sort -----------------
// order: score descending, ties -> smaller index first (matches lax.top_k)
__global__ void topk_sort(const float* __restrict__ scores,
                          float* __restrict__ vals, int* __restrict__ idx)
{
    __shared__ float sk[2048];
    __shared__ int si[2048];
    const int tid = threadIdx.x;                 // 1024
    sk[tid] = scores[tid];           si[tid] = tid;
    sk[tid + 1024] = scores[tid + 1024]; si[tid + 1024] = tid + 1024;
    __syncthreads();
    for (int k = 2; k <= 2048; k <<= 1) {
        for (int j = k >> 1; j > 0; j >>= 1) {
#pragma unroll 1
            for (int t = tid; t < 2048; t += 1024) {
                int l = t ^ j;
                if (l > t) {
                    float a = sk[t], b = sk[l];
                    int ia = si[t], ib = si[l];
                    bool aFirst = (a > b) || (a == b && ia < ib);
                    bool up = ((t & k) == 0);
                    if (up ? !aFirst : aFirst) {
                        sk[t] = b; sk[l] = a; si[t] = ib; si[l] = ia;
                    }
                }
            }
            __syncthreads();
        }
    }
    vals[tid] = sk[tid];
    idx[tid] = si[tid];
}

// ------------- new_h = f[idx] * vals --------------------------------------
__global__ void gather_scale(const float* __restrict__ f_gt,
                             const float* __restrict__ f_gs,
                             const int* __restrict__ idx,
                             const float* __restrict__ vals,
                             float* __restrict__ new_ht,
                             float* __restrict__ new_hs)
{
    const int p = blockIdx.x;                    // 1024
    const int d = threadIdx.x;                   // 128
    const int s = idx[p];
    const float v = vals[p];
    new_ht[(size_t)p * 128 + d] = f_gt[(size_t)s * 128 + d] * v;
    new_hs[(size_t)p * 128 + d] = f_gs[(size_t)s * 128 + d] * v;
}

// ------------- Ap[p][q] = any(bits[idx[p]] & bits[idx[q]]) ------------------
// un2 = (un@un)>0 with un symmetric 0/1; only pooled submatrix needed.
__global__ void build_ap(const unsigned long long* __restrict__ bits,
                         const int* __restrict__ idx, float* __restrict__ Ap)
{
    __shared__ unsigned long long pb[16][32];
    __shared__ unsigned long long qb[16][32];
    const int tp = blockIdx.y * 16;
    const int tq = blockIdx.x * 16;
    const int tid = threadIdx.x;                 // 256
    for (int t = tid; t < 512; t += 256) {
        int r = t >> 5, w = t & 31;
        pb[r][w] = bits[(size_t)idx[tp + r] * 32 + w];
        qb[r][w] = bits[(size_t)idx[tq + r] * 32 + w];
    }
    __syncthreads();
    const int pi = tid >> 4, qi = tid & 15;
    unsigned long long acc = 0;
#pragma unroll
    for (int w = 0; w < 32; ++w) acc |= (pb[pi][w] & qb[qi][w]);
    Ap[(size_t)(tp + pi) * 1024 + tq + qi] = acc ? 1.0f : 0.0f;
}

// ------------- row sum -> 1/sqrt(max(deg,1e-12)) ---------------------------
__global__ void rowsum_rsqrt(const float* __restrict__ Ap,
                             float* __restrict__ dinvp, int n)
{
    const int row = blockIdx.x;
    const int tid = threadIdx.x;                 // 256
    float s = 0.0f;
    for (int j = tid; j < n; j += 256) s += Ap[(size_t)row * n + j];
    __shared__ float red[256];
    red[tid] = s;
    __syncthreads();
    for (int st = 128; st > 0; st >>= 1) {
        if (tid < st) red[tid] += red[tid + st];
        __syncthreads();
    }
    if (tid == 0) dinvp[row] = 1.0f / sqrtf(fmaxf(red[0], 1e-12f));
}

__global__ void zero1(float* __restrict__ p) { p[0] = 0.0f; }

// ---------------------------------------------------------------------------
extern "C" void kernel_launch(void* const* d_in, const int* in_sizes, int n_in,
                              void* d_out, int out_size, void* d_ws, size_t ws_size,
                              hipStream_t stream)
{
    (void)in_sizes; (void)n_in; (void)out_size; (void)ws_size;
    const float* fs      = (const float*)d_in[0];
    const float* ft      = (const float*)d_in[1];
    const float* W_embed = (const float*)d_in[2];
    const float* b_embed = (const float*)d_in[3];
    const float* W_gnn   = (const float*)d_in[4];
    const float* b_gnn   = (const float*)d_in[5];
    const float* W_pool  = (const float*)d_in[6];
    const float* b_pool  = (const float*)d_in[7];
    const float* W_gnnp  = (const float*)d_in[8];
    const float* b_gnnp  = (const float*)d_in[9];
    float* out = (float*)d_out;

    // workspace layout (floats); total ~10.76M floats ~= 43 MB
    float* ws = (float*)d_ws;
    size_t o = 0;
    auto alloc = [&](size_t n) { float* p = ws + o; o += n; return p; };
    float* bigA   = alloc(2048ull * 2048);       // A -> An -> G (NCE)
    float* bigB   = alloc(2048ull * 2048);       // G2 -> {Ap, Gp, Gp2}
    float* f_es   = alloc(2048 * 128);
    float* f_et   = alloc(2048 * 128);
    float* f_gt   = alloc(2048 * 128);
    float* f_gs   = alloc(2048 * 128);
    float* h1     = alloc(2048 * 128);
    float* h2     = alloc(2048 * 128);
    float* dinv   = alloc(2048);
    float* scores = alloc(2048);
    float* vals   = alloc(1024);
    int*   idxb   = (int*)alloc(1024);
    unsigned long long* bits = (unsigned long long*)alloc(2048 * 32 * 2);
    float* new_ht = alloc(1024 * 128);
    float* new_hs = alloc(1024 * 128);
    float* tmp_p  = alloc(1024 * 128);
    float* f_pt   = alloc(1024 * 128);
    float* f_ps   = alloc(1024 * 128);
    float* dinvp  = alloc(1024);
    float* Ap  = bigB;
    float* Gp  = bigB + 1024ull * 1024;
    float* Gp2 = bigB + 2ull * 1024 * 1024;

    zero1<<<1, 1, 0, stream>>>(out);

    // ---- embed + l2norm ----
    gemm64<false, 1><<<dim3(2, 32), 256, 0, stream>>>(fs, 512, W_embed, 128, b_embed, f_es, 128, 512);
    gemm64<false, 1><<<dim3(2, 32), 256, 0, stream>>>(ft, 512, W_embed, 128, b_embed, f_et, 128, 512);
    l2norm_rows<<<2048, 128, 0, stream>>>(f_es);
    l2norm_rows<<<2048, 128, 0, stream>>>(f_et);

    // ---- adjacency: A = (f_et f_et^T > 0), self loops; bits; dinv; An ----
    gemm64<true, 0><<<dim3(32, 32), 256, 0, stream>>>(f_et, 128, f_et, 128, nullptr, bigA, 2048, 128);
    threshold_pack<<<2048, 256, 0, stream>>>(bigA, bits, dinv);
    scale_adj<<<16384, 256, 0, stream>>>(bigA, dinv, 11);

    // ---- TAGConv (k=2) teacher ----
    gemm64<false, 0><<<dim3(2, 32), 256, 0, stream>>>(bigA, 2048, f_et, 128, nullptr, h1, 128, 2048);
    gemm64<false, 0><<<dim3(2, 32), 256, 0, stream>>>(bigA, 2048, h1, 128, nullptr, h2, 128, 2048);
    gemm64<false, 1><<<dim3(2, 32), 256, 0, stream>>>(f_et, 128, W_gnn, 128, b_gnn, f_gt, 128, 128);
    gemm64<false, 2><<<dim3(2, 32), 256, 0, stream>>>(h1, 128, W_gnn + 128 * 128, 128, nullptr, f_gt, 128, 128);
    gemm64<false, 2><<<dim3(2, 32), 256, 0, stream>>>(h2, 128, W_gnn + 256 * 128, 128, nullptr, f_gt, 128, 128);
    l2norm_rows<<<2048, 128, 0, stream>>>(f_gt);

    // ---- TAGConv (k=2) student ----
    gemm64<false, 0><<<dim3(2, 32), 256, 0, stream>>>(bigA, 2048, f_es, 128, nullptr, h1, 128, 2048);
    gemm64<false, 0><<<dim3(2, 32), 256, 0, stream>>>(bigA, 2048, h1, 128, nullptr, h2, 128, 2048);
    gemm64<false, 1><<<dim3(2, 32), 256, 0, stream>>>(f_es, 128, W_gnn, 128, b_gnn, f_gs, 128, 128);
    gemm64<false, 2><<<dim3(2, 32), 256, 0, stream>>>(h1, 128, W_gnn + 128 * 128, 128, nullptr, f_gs, 128, 128);
    gemm64<false, 2><<<dim3(2, 32), 256, 0, stream>>>(h2, 128, W_gnn + 256 * 128, 128, nullptr, f_gs, 128, 128);
    l2norm_rows<<<2048, 128, 0, stream>>>(f_gs);

    // ---- graph-level NCE ----
    gemm64<true, 0><<<dim3(32, 32), 256, 0, stream>>>(f_gt, 128, f_gs, 128, nullptr, bigA, 2048, 128);
    gemm64<true, 0><<<dim3(32, 32), 256, 0, stream>>>(f_gs, 128, f_gt, 128, nullptr, bigB, 2048, 128);
    nce_rows<<<2048, 256, 0, stream>>>(bigA, 2048, 1.0f / 2048.0f, out);
    nce_rows<<<2048, 256, 0, stream>>>(bigB, 2048, 1.0f / 2048.0f, out);

    // ---- pooling ----
    pool_score<<<2048, 128, 0, stream>>>(f_gt, W_pool, b_pool, scores);
    topk_sort<<<1, 1024, 0, stream>>>(scores, vals, idxb);
    gather_scale<<<1024, 128, 0, stream>>>(f_gt, f_gs, idxb, vals, new_ht, new_hs);
    build_ap<<<dim3(64, 64), 256, 0, stream>>>(bits, idxb, Ap);
    rowsum_rsqrt<<<1024, 256, 0, stream>>>(Ap, dinvp, 1024);
    scale_adj<<<4096, 256, 0, stream>>>(Ap, dinvp, 10);   // Ap -> Anp

    // ---- pooled TAGConv (k=1) teacher ----
    gemm64<false, 0><<<dim3(2, 16), 256, 0, stream>>>(Ap, 1024, new_ht, 128, nullptr, tmp_p, 128, 1024);
    gemm64<false, 1><<<dim3(2, 16), 256, 0, stream>>>(new_ht, 128, W_gnnp, 128, b_gnnp, f_pt, 128, 128);
    gemm64<false, 2><<<dim3(2, 16), 256, 0, stream>>>(tmp_p, 128, W_gnnp + 128 * 128, 128, nullptr, f_pt, 128, 128);
    l2norm_rows<<<1024, 128, 0, stream>>>(f_pt);
    // ---- pooled TAGConv (k=1) student ----
    gemm64<false, 0><<<dim3(2, 16), 256, 0, stream>>>(Ap, 1024, new_hs, 128, nullptr, tmp_p, 128, 1024);
    gemm64<false, 1><<<dim3(2, 16), 256, 0, stream>>>(new_hs, 128, W_gnnp, 128, b_gnnp, f_ps, 128, 128);
    gemm64<false, 2><<<dim3(2, 16), 256, 0, stream>>>(tmp_p, 128, W_gnnp + 128 * 128, 128, nullptr, f_ps, 128, 128);
    l2norm_rows<<<1024, 128, 0, stream>>>(f_ps);

    // ---- pooled NCE ----
    gemm64<true, 0><<<dim3(16, 16), 256, 0, stream>>>(f_pt, 128, f_ps, 128, nullptr, Gp, 1024, 128);
    gemm64<true, 0><<<dim3(16, 16), 256, 0, stream>>>(f_ps, 128, f_pt, 128, nullptr, Gp2, 1024, 128);
    nce_rows<<<1024, 256, 0, stream>>>(Gp, 1024, 1.0f / 1024.0f, out);
    nce_rows<<<1024, 256, 0, stream>>>(Gp2, 1024, 1.0f / 1024.0f, out);
}

// Round 2
// 572.221 us; speedup vs baseline: 1.8973x; 1.8973x over previous
//
#include <hip/hip_runtime.h>

// ---------------------------------------------------------------------------
// GNNLoss fp32. N=2048, C=512, D=128, K_POOL=1024, T=0.07, NEG=-10.
// Round 2: split-K skinny GEMMs, fused TAGConv-linear+l2norm, gram dedup
// (NCE second gram = transpose; adjacency gram = symmetric/triangular).
// ---------------------------------------------------------------------------

#define TINV (1.0f / 0.07f)
#define NEGF (-10.0f)

// ---------------- shared 64x64 tile core -----------------------------------
// BT=false: B is [K,N] row-major. BT=true: B is [N,K] row-major (A @ B^T).
template<bool BT>
__device__ __forceinline__ void mm_tile(const float* __restrict__ A, int lda,
                                        const float* __restrict__ B, int ldb,
                                        int i0, int j0, int k0, int k1,
                                        float (&acc)[4][4],
                                        float (&As)[16][68], float (&Bs)[16][68])
{
    const int tid = threadIdx.x;
    const int tx = tid & 15;
    const int ty = tid >> 4;
    const int lr = tid >> 2;        // 0..63
    const int lc = (tid & 3) * 4;   // 0,4,8,12
    for (int k = k0; k < k1; k += 16) {
        float4 av = *(const float4*)(A + (size_t)(i0 + lr) * lda + (k + lc));
        As[lc + 0][lr] = av.x; As[lc + 1][lr] = av.y;
        As[lc + 2][lr] = av.z; As[lc + 3][lr] = av.w;
        if (BT) {
            float4 bv = *(const float4*)(B + (size_t)(j0 + lr) * ldb + (k + lc));
            Bs[lc + 0][lr] = bv.x; Bs[lc + 1][lr] = bv.y;
            Bs[lc + 2][lr] = bv.z; Bs[lc + 3][lr] = bv.w;
        } else {
            const int n = tid & 63;
            const int kb = tid >> 6;
#pragma unroll
            for (int it = 0; it < 4; ++it)
                Bs[kb * 4 + it][n] = B[(size_t)(k + kb * 4 + it) * ldb + (j0 + n)];
        }
        __syncthreads();
#pragma unroll
        for (int kk = 0; kk < 16; ++kk) {
            float a[4], b[4];
#pragma unroll
            for (int u = 0; u < 4; ++u) a[u] = As[kk][ty * 4 + u];
#pragma unroll
            for (int v = 0; v < 4; ++v) b[v] = Bs[kk][tx * 4 + v];
#pragma unroll
            for (int u = 0; u < 4; ++u)
#pragma unroll
                for (int v = 0; v < 4; ++v)
                    acc[u][v] = fmaf(a[u], b[v], acc[u][v]);
        }
        __syncthreads();
    }
}

// ---------------- split-K GEMM: partial[z] = A[:,zKc:(z+1)Kc] @ B ----------
// A [M,lda], B [K,128] row-major, out partial z at part + z*zstride, ldc=128.
__launch_bounds__(256)
__global__ void gemm64_sk(const float* __restrict__ A, int lda,
                          const float* __restrict__ B,
                          float* __restrict__ part, int Kc, size_t zstride)
{
    __shared__ float As[16][68];
    __shared__ float Bs[16][68];
    const int i0 = blockIdx.y * 64;
    const int j0 = blockIdx.x * 64;
    const int k0 = blockIdx.z * Kc;
    float acc[4][4] = {};
    mm_tile<false>(A, lda, B, 128, i0, j0, k0, k0 + Kc, acc, As, Bs);
    const int tid = threadIdx.x;
    const int tx = tid & 15, ty = tid >> 4;
    float* dst = part + blockIdx.z * zstride;
#pragma unroll
    for (int u = 0; u < 4; ++u) {
        const size_t ri = (size_t)(i0 + ty * 4 + u) * 128 + j0 + tx * 4;
#pragma unroll
        for (int v = 0; v < 4; ++v) dst[ri + v] = acc[u][v];
    }
}

// ---------------- TAGConv linear, batched over hop terms -------------------
// partial[z] = A_z @ W[z*128*128 ...], A_z in {A0,A1,A2}, all [M,128].
__launch_bounds__(256)
__global__ void gemm_tag(const float* __restrict__ A0, const float* __restrict__ A1,
                         const float* __restrict__ A2, const float* __restrict__ W,
                         float* __restrict__ part, size_t zstride)
{
    __shared__ float As[16][68];
    __shared__ float Bs[16][68];
    const int z = blockIdx.z;
    const float* A = (z == 0) ? A0 : (z == 1) ? A1 : A2;
    const float* B = W + (size_t)z * 128 * 128;
    const int i0 = blockIdx.y * 64;
    const int j0 = blockIdx.x * 64;
    float acc[4][4] = {};
    mm_tile<false>(A, 128, B, 128, i0, j0, 0, 128, acc, As, Bs);
    const int tid = threadIdx.x;
    const int tx = tid & 15, ty = tid >> 4;
    float* dst = part + z * zstride;
#pragma unroll
    for (int u = 0; u < 4; ++u) {
        const size_t ri = (size_t)(i0 + ty * 4 + u) * 128 + j0 + tx * 4;
#pragma unroll
        for (int v = 0; v < 4; ++v) dst[ri + v] = acc[u][v];
    }
}

// ---------------- gram with dual store: C = A@B^T, CT = C^T ----------------
// TRI: triangular grid (A==B symmetric result), skip transposed store on diag.
template<bool TRI>
__launch_bounds__(256)
__global__ void gram_both(const float* __restrict__ A, const float* __restrict__ B,
                          float* __restrict__ C, float* __restrict__ CT, int n)
{
    __shared__ float As[16][68];
    __shared__ float Bs[16][68];
    __shared__ float Ts[64][68];
    int bx, by;
    if (TRI) {
        const int b = blockIdx.x;
        by = (int)((sqrtf(8.0f * b + 1.0f) - 1.0f) * 0.5f);
        while ((by + 1) * (by + 2) / 2 <= b) ++by;
        while (by * (by + 1) / 2 > b) --by;
        bx = b - by * (by + 1) / 2;
    } else { bx = blockIdx.x; by = blockIdx.y; }
    const int i0 = by * 64, j0 = bx * 64;
    float acc[4][4] = {};
    mm_tile<true>(A, 128, B, 128, i0, j0, 0, 128, acc, As, Bs);
    const int tid = threadIdx.x;
    const int tx = tid & 15, ty = tid >> 4;
#pragma unroll
    for (int u = 0; u < 4; ++u) {
        const size_t ri = (size_t)(i0 + ty * 4 + u) * n + j0 + tx * 4;
#pragma unroll
        for (int v = 0; v < 4; ++v) {
            C[ri + v] = acc[u][v];
            Ts[tx * 4 + v][ty * 4 + u] = acc[u][v];
        }
    }
    if (TRI && bx == by) return;     // diagonal tile: mirror == self
    __syncthreads();
    // transposed tile -> CT at (j0, i0), coalesced float4 stores
    const int r = tid >> 2;          // 0..63
    const int c0 = (tid & 3) * 16;   // 16 floats per thread
#pragma unroll
    for (int m = 0; m < 4; ++m) {
        float4 v = *(const float4*)&Ts[r][c0 + m * 4];
        *(float4*)(CT + (size_t)(j0 + r) * n + i0 + c0 + m * 4) = v;
    }
}

// ---------------- reduce split-K partials (float4) -------------------------
__global__ void reduce_add(float* __restrict__ out, const float* __restrict__ part,
                           int nz, size_t zstride)
{
    const size_t i = (size_t)blockIdx.x * 256 + threadIdx.x;
    const float4* p = (const float4*)part;
    const size_t zs4 = zstride >> 2;
    float4 s = p[i];
    for (int z = 1; z < nz; ++z) {
        float4 t = p[z * zs4 + i];
        s.x += t.x; s.y += t.y; s.z += t.z; s.w += t.w;
    }
    ((float4*)out)[i] = s;
}

// ---------------- combine partials + bias + row l2norm ---------------------
__global__ void combine_l2norm(float* __restrict__ out, const float* __restrict__ part,
                               const float* __restrict__ bias, int nz, size_t zstride)
{
    const int row = blockIdx.x;
    const int tid = threadIdx.x;                 // 128
    float v = bias[tid];
    for (int z = 0; z < nz; ++z) v += part[z * zstride + (size_t)row * 128 + tid];
    __shared__ float red[128];
    red[tid] = v * v;
    __syncthreads();
    for (int s = 64; s > 0; s >>= 1) {
        if (tid < s) red[tid] += red[tid + s];
        __syncthreads();
    }
    out[(size_t)row * 128 + tid] = v * (1.0f / sqrtf(red[0]));
}

// ------------- threshold gram -> A(0/1), pack bits, deg -> dinv ------------
__global__ void threshold_pack(float* __restrict__ G,
                               unsigned long long* __restrict__ bits,
                               float* __restrict__ dinv)
{
    const int row = blockIdx.x;
    const int tid = threadIdx.x;
    const int lane = tid & 63;
    const int wave = tid >> 6;
    int total = 0;
    for (int c = 0; c < 8; ++c) {
        const int chunk = wave * 8 + c;
        const int j = chunk * 64 + lane;
        float g = G[(size_t)row * 2048 + j];
        bool a = (j == row) ? true : (g > 0.0f);
        unsigned long long m = __ballot(a);
        G[(size_t)row * 2048 + j] = a ? 1.0f : 0.0f;
        if (lane == 0) bits[(size_t)row * 32 + chunk] = m;
        total += __popcll(m);
    }
    __shared__ int wred[4];
    if (lane == 0) wred[wave] = total;
    __syncthreads();
    if (tid == 0) {
        float deg = (float)(wred[0] + wred[1] + wred[2] + wred[3]);
        dinv[row] = 1.0f / sqrtf(deg);
    }
}

// ------------- A(0/1) -> An = A * dinv_i * dinv_j, in place ----------------
__global__ void scale_adj(float* __restrict__ A, const float* __restrict__ dinv,
                          int logn)
{
    const size_t idx = (size_t)blockIdx.x * 256 + threadIdx.x;
    const int i = (int)(idx >> logn);
    const int j = (int)(idx & ((1u << logn) - 1));
    float a = A[idx];
    A[idx] = (a != 0.0f) ? dinv[i] * dinv[j] : 0.0f;
}

// ------------- NCE row term: mean_i (LSE_i - pos_i/T) ----------------------
__global__ void nce_rows(const float* __restrict__ G, int n, float invN,
                         float* __restrict__ out)
{
    const int row = blockIdx.x;
    const int tid = threadIdx.x;
    const float pos = G[(size_t)row * n + row];
    float m = pos;
    for (int j = tid; j < n; j += 256) {
        float g = (j == row) ? NEGF : G[(size_t)row * n + j];
        m = fmaxf(m, g);
    }
    __shared__ float red[256];
    red[tid] = m;
    __syncthreads();
    for (int s = 128; s > 0; s >>= 1) {
        if (tid < s) red[tid] = fmaxf(red[tid], red[tid + s]);
        __syncthreads();
    }
    m = red[0];
    __syncthreads();
    float ssum = (tid == 0) ? expf((pos - m) * TINV) : 0.0f;
    for (int j = tid; j < n; j += 256) {
        float g = (j == row) ? NEGF : G[(size_t)row * n + j];
        ssum += expf((g - m) * TINV);
    }
    red[tid] = ssum;
    __syncthreads();
    for (int s = 128; s > 0; s >>= 1) {
        if (tid < s) red[tid] += red[tid + s];
        __syncthreads();
    }
    if (tid == 0)
        atomicAdd(out, (logf(red[0]) + (m - pos) * TINV) * invN);
}

// ------------- pooling score: sigmoid(f_gt @ W_pool + b) -------------------
__global__ void pool_score(const float* __restrict__ f,
                           const float* __restrict__ Wp,
                           const float* __restrict__ bp,
                           float* __restrict__ scores)
{
    const int row = blockIdx.x;
    const int tid = threadIdx.x;                 // 128
    float v = f[(size_t)row * 128 + tid] * Wp[tid];
    __shared__ float red[128];
    red[tid] = v;
    __syncthreads();
    for (int s = 64; s > 0; s >>= 1) {
        if (tid < s) red[tid] += red[tid + s];
        __syncthreads();
    }
    if (tid == 0) scores[row] = 1.0f / (1.0f + expf(-(red[0] + bp[0])));
}

// ------------- top-1024 of 2048: single-block bitonic sort -----------------
__global__ void topk_sort(const float* __restrict__ scores,
                          float* __restrict__ vals, int* __restrict__ idx)
{
    __shared__ float sk[2048];
    __shared__ int si[2048];
    const int tid = threadIdx.x;                 // 1024
    sk[tid] = scores[tid];               si[tid] = tid;
    sk[tid + 1024] = scores[tid + 1024]; si[tid + 1024] = tid + 1024;
    __syncthreads();
    for (int k = 2; k <= 2048; k <<= 1) {
        for (int j = k >> 1; j > 0; j >>= 1) {
#pragma unroll 1
            for (int t = tid; t < 2048; t += 1024) {
                int l = t ^ j;
                if (l > t) {
                    float a = sk[t], b = sk[l];
                    int ia = si[t], ib = si[l];
                    bool aFirst = (a > b) || (a == b && ia < ib);
                    bool up = ((t & k) == 0);
                    if (up ? !aFirst : aFirst) {
                        sk[t] = b; sk[l] = a; si[t] = ib; si[l] = ia;
                    }
                }
            }
            __syncthreads();
        }
    }
    vals[tid] = sk[tid];
    idx[tid] = si[tid];
}

// ------------- new_h = f[idx] * vals --------------------------------------
__global__ void gather_scale(const float* __restrict__ f_gt,
                             const float* __restrict__ f_gs,
                             const int* __restrict__ idx,
                             const float* __restrict__ vals,
                             float* __restrict__ new_ht,
                             float* __restrict__ new_hs)
{
    const int p = blockIdx.x;
    const int d = threadIdx.x;                   // 128
    const int s = idx[p];
    const float v = vals[p];
    new_ht[(size_t)p * 128 + d] = f_gt[(size_t)s * 128 + d] * v;
    new_hs[(size_t)p * 128 + d] = f_gs[(size_t)s * 128 + d] * v;
}

// ------------- Ap[p][q] = any(bits[idx[p]] & bits[idx[q]]) ------------------
__global__ void build_ap(const unsigned long long* __restrict__ bits,
                         const int* __restrict__ idx, float* __restrict__ Ap)
{
    __shared__ unsigned long long pb[16][32];
    __shared__ unsigned long long qb[16][32];
    const int tp = blockIdx.y * 16;
    const int tq = blockIdx.x * 16;
    const int tid = threadIdx.x;                 // 256
    for (int t = tid; t < 512; t += 256) {
        int r = t >> 5, w = t & 31;
        pb[r][w] = bits[(size_t)idx[tp + r] * 32 + w];
        qb[r][w] = bits[(size_t)idx[tq + r] * 32 + w];
    }
    __syncthreads();
    const int pi = tid >> 4, qi = tid & 15;
    unsigned long long acc = 0;
#pragma unroll
    for (int w = 0; w < 32; ++w) acc |= (pb[pi][w] & qb[qi][w]);
    Ap[(size_t)(tp + pi) * 1024 + tq + qi] = acc ? 1.0f : 0.0f;
}

// ------------- row sum -> 1/sqrt(max(deg,1e-12)) ---------------------------
__global__ void rowsum_rsqrt(const float* __restrict__ Ap,
                             float* __restrict__ dinvp, int n)
{
    const int row = blockIdx.x;
    const int tid = threadIdx.x;                 // 256
    float s = 0.0f;
    for (int j = tid; j < n; j += 256) s += Ap[(size_t)row * n + j];
    __shared__ float red[256];
    red[tid] = s;
    __syncthreads();
    for (int st = 128; st > 0; st >>= 1) {
        if (tid < st) red[tid] += red[tid + st];
        __syncthreads();
    }
    if (tid == 0) dinvp[row] = 1.0f / sqrtf(fmaxf(red[0], 1e-12f));
}

__global__ void zero1(float* __restrict__ p) { p[0] = 0.0f; }

// ---------------------------------------------------------------------------
extern "C" void kernel_launch(void* const* d_in, const int* in_sizes, int n_in,
                              void* d_out, int out_size, void* d_ws, size_t ws_size,
                              hipStream_t stream)
{
    (void)in_sizes; (void)n_in; (void)out_size; (void)ws_size;
    const float* fs      = (const float*)d_in[0];
    const float* ft      = (const float*)d_in[1];
    const float* W_embed = (const float*)d_in[2];
    const float* b_embed = (const float*)d_in[3];
    const float* W_gnn   = (const float*)d_in[4];
    const float* b_gnn   = (const float*)d_in[5];
    const float* W_pool  = (const float*)d_in[6];
    const float* b_pool  = (const float*)d_in[7];
    const float* W_gnnp  = (const float*)d_in[8];
    const float* b_gnnp  = (const float*)d_in[9];
    float* out = (float*)d_out;

    float* ws = (float*)d_ws;
    size_t o = 0;
    auto alloc = [&](size_t n) { float* p = ws + o; o += n; return p; };
    float* bigA   = alloc(2048ull * 2048);       // An -> G1 (NCE)
    float* bigB   = alloc(2048ull * 2048);       // partials -> G2 -> pooled region
    float* f_es   = alloc(2048 * 128);
    float* f_et   = alloc(2048 * 128);
    float* f_gt   = alloc(2048 * 128);
    float* f_gs   = alloc(2048 * 128);
    float* h1     = alloc(2048 * 128);
    float* h2     = alloc(2048 * 128);
    float* dinv   = alloc(2048);
    float* scores = alloc(2048);
    float* vals   = alloc(1024);
    int*   idxb   = (int*)alloc(1024);
    unsigned long long* bits = (unsigned long long*)alloc(2048 * 32 * 2);
    float* new_ht = alloc(1024 * 128);
    float* new_hs = alloc(1024 * 128);
    float* tmp_p  = alloc(1024 * 128);
    float* f_pt   = alloc(1024 * 128);
    float* f_ps   = alloc(1024 * 128);
    float* dinvp  = alloc(1024);

    const size_t NSTR = 2048ull * 128;           // full-graph partial stride
    const size_t PSTR = 1024ull * 128;           // pooled partial stride
    float* part  = bigB;                         // up to 8 partials (8 MB)
    float* Ap    = bigB;                         // pooled region reuses bigB
    float* Gp    = bigB + 1024ull * 1024;
    float* Gp2   = bigB + 2ull * 1024 * 1024;
    float* partP = bigB + 3ull * 1024 * 1024;    // pooled partials (2 MB)

    zero1<<<1, 1, 0, stream>>>(out);

    // ---- embed + l2norm (split-K 4 over C=512) ----
    gemm64_sk<<<dim3(2, 32, 4), 256, 0, stream>>>(fs, 512, W_embed, part, 128, NSTR);
    combine_l2norm<<<2048, 128, 0, stream>>>(f_es, part, b_embed, 4, NSTR);
    gemm64_sk<<<dim3(2, 32, 4), 256, 0, stream>>>(ft, 512, W_embed, part, 128, NSTR);
    combine_l2norm<<<2048, 128, 0, stream>>>(f_et, part, b_embed, 4, NSTR);

    // ---- adjacency: symmetric gram (triangular grid), threshold, normalize ----
    gram_both<true><<<528, 256, 0, stream>>>(f_et, f_et, bigA, bigA, 2048);
    threshold_pack<<<2048, 256, 0, stream>>>(bigA, bits, dinv);
    scale_adj<<<16384, 256, 0, stream>>>(bigA, dinv, 11);

    // ---- TAGConv (k=2) teacher ----
    gemm64_sk<<<dim3(2, 32, 8), 256, 0, stream>>>(bigA, 2048, f_et, part, 256, NSTR);
    reduce_add<<<256, 256, 0, stream>>>(h1, part, 8, NSTR);
    gemm64_sk<<<dim3(2, 32, 8), 256, 0, stream>>>(bigA, 2048, h1, part, 256, NSTR);
    reduce_add<<<256, 256, 0, stream>>>(h2, part, 8, NSTR);
    gemm_tag<<<dim3(2, 32, 3), 256, 0, stream>>>(f_et, h1, h2, W_gnn, part, NSTR);
    combine_l2norm<<<2048, 128, 0, stream>>>(f_gt, part, b_gnn, 3, NSTR);

    // ---- TAGConv (k=2) student ----
    gemm64_sk<<<dim3(2, 32, 8), 256, 0, stream>>>(bigA, 2048, f_es, part, 256, NSTR);
    reduce_add<<<256, 256, 0, stream>>>(h1, part, 8, NSTR);
    gemm64_sk<<<dim3(2, 32, 8), 256, 0, stream>>>(bigA, 2048, h1, part, 256, NSTR);
    reduce_add<<<256, 256, 0, stream>>>(h2, part, 8, NSTR);
    gemm_tag<<<dim3(2, 32, 3), 256, 0, stream>>>(f_es, h1, h2, W_gnn, part, NSTR);
    combine_l2norm<<<2048, 128, 0, stream>>>(f_gs, part, b_gnn, 3, NSTR);

    // ---- graph-level NCE: one gram, dual store (G2 = G1^T) ----
    gram_both<false><<<dim3(32, 32), 256, 0, stream>>>(f_gt, f_gs, bigA, bigB, 2048);
    nce_rows<<<2048, 256, 0, stream>>>(bigA, 2048, 1.0f / 2048.0f, out);
    nce_rows<<<2048, 256, 0, stream>>>(bigB, 2048, 1.0f / 2048.0f, out);

    // ---- pooling ----
    pool_score<<<2048, 128, 0, stream>>>(f_gt, W_pool, b_pool, scores);
    topk_sort<<<1, 1024, 0, stream>>>(scores, vals, idxb);
    gather_scale<<<1024, 128, 0, stream>>>(f_gt, f_gs, idxb, vals, new_ht, new_hs);
    build_ap<<<dim3(64, 64), 256, 0, stream>>>(bits, idxb, Ap);
    rowsum_rsqrt<<<1024, 256, 0, stream>>>(Ap, dinvp, 1024);
    scale_adj<<<4096, 256, 0, stream>>>(Ap, dinvp, 10);

    // ---- pooled TAGConv (k=1) teacher ----
    gemm64_sk<<<dim3(2, 16, 4), 256, 0, stream>>>(Ap, 1024, new_ht, partP, 256, PSTR);
    reduce_add<<<128, 256, 0, stream>>>(tmp_p, partP, 4, PSTR);
    gemm_tag<<<dim3(2, 16, 2), 256, 0, stream>>>(new_ht, tmp_p, nullptr, W_gnnp, partP, PSTR);
    combine_l2norm<<<1024, 128, 0, stream>>>(f_pt, partP, b_gnnp, 2, PSTR);

    // ---- pooled TAGConv (k=1) student ----
    gemm64_sk<<<dim3(2, 16, 4), 256, 0, stream>>>(Ap, 1024, new_hs, partP, 256, PSTR);
    reduce_add<<<128, 256, 0, stream>>>(tmp_p, partP, 4, PSTR);
    gemm_tag<<<dim3(2, 16, 2), 256, 0, stream>>>(new_hs, tmp_p, nullptr, W_gnnp, partP, PSTR);
    combine_l2norm<<<1024, 128, 0, stream>>>(f_ps, partP, b_gnnp, 2, PSTR);

    // ---- pooled NCE: one gram, dual store ----
    gram_both<false><<<dim3(16, 16), 256, 0, stream>>>(f_pt, f_ps, Gp, Gp2, 1024);
    nce_rows<<<1024, 256, 0, stream>>>(Gp, 1024, 1.0f / 1024.0f, out);
    nce_rows<<<1024, 256, 0, stream>>>(Gp2, 1024, 1.0f / 1024.0f, out);
}

// Round 3
// 363.588 us; speedup vs baseline: 2.9860x; 1.5738x over previous
//
#include <hip/hip_runtime.h>

// ---------------------------------------------------------------------------
// GNNLoss. N=2048, C=512, D=128, K_POOL=1024, T=0.07, NEG=-10.
// Round 3: bf16 MFMA for hops/tag-linears/NCE-grams (A01 is exact in bf16);
// fp32 only for embed + adjacency gram (discrete threshold); teacher+student
// merged (N=256 hops, M=4096 tags); radix-select top-k.
// ---------------------------------------------------------------------------

#define TINV (1.0f / 0.07f)
#define NEGF (-10.0f)

using short8 = __attribute__((ext_vector_type(8))) short;
using f32x4  = __attribute__((ext_vector_type(4))) float;

__device__ __forceinline__ unsigned short f2bf(float f) {
    unsigned u = __float_as_uint(f);
    u += 0x7fff + ((u >> 16) & 1);
    return (unsigned short)(u >> 16);
}

// ---------------- fp32 64x64 tile core (round-2, verified) -----------------
template<bool BT>
__device__ __forceinline__ void mm_tile(const float* __restrict__ A, int lda,
                                        const float* __restrict__ B, int ldb,
                                        int i0, int j0, int k0, int k1,
                                        float (&acc)[4][4],
                                        float (&As)[16][68], float (&Bs)[16][68])
{
    const int tid = threadIdx.x;
    const int tx = tid & 15;
    const int ty = tid >> 4;
    const int lr = tid >> 2;
    const int lc = (tid & 3) * 4;
    for (int k = k0; k < k1; k += 16) {
        float4 av = *(const float4*)(A + (size_t)(i0 + lr) * lda + (k + lc));
        As[lc + 0][lr] = av.x; As[lc + 1][lr] = av.y;
        As[lc + 2][lr] = av.z; As[lc + 3][lr] = av.w;
        if (BT) {
            float4 bv = *(const float4*)(B + (size_t)(j0 + lr) * ldb + (k + lc));
            Bs[lc + 0][lr] = bv.x; Bs[lc + 1][lr] = bv.y;
            Bs[lc + 2][lr] = bv.z; Bs[lc + 3][lr] = bv.w;
        } else {
            const int n = tid & 63;
            const int kb = tid >> 6;
#pragma unroll
            for (int it = 0; it < 4; ++it)
                Bs[kb * 4 + it][n] = B[(size_t)(k + kb * 4 + it) * ldb + (j0 + n)];
        }
        __syncthreads();
#pragma unroll
        for (int kk = 0; kk < 16; ++kk) {
            float a[4], b[4];
#pragma unroll
            for (int u = 0; u < 4; ++u) a[u] = As[kk][ty * 4 + u];
#pragma unroll
            for (int v = 0; v < 4; ++v) b[v] = Bs[kk][tx * 4 + v];
#pragma unroll
            for (int u = 0; u < 4; ++u)
#pragma unroll
                for (int v = 0; v < 4; ++v)
                    acc[u][v] = fmaf(a[u], b[v], acc[u][v]);
        }
        __syncthreads();
    }
}

// ---------------- fp32 embed GEMM, teacher+student merged ------------------
// grid (2, 64, 4). rows 0..2047 = ft, 2048..4095 = fs. split-K over C=512.
__launch_bounds__(256)
__global__ void gemm_embed(const float* __restrict__ fs, const float* __restrict__ ft,
                           const float* __restrict__ W, float* __restrict__ part,
                           size_t zstr)
{
    __shared__ float As[16][68];
    __shared__ float Bs[16][68];
    const int by = blockIdx.y;
    const float* A = (by < 32) ? ft : fs;
    const int i0 = (by < 32) ? by * 64 : (by - 32) * 64;
    const int j0 = blockIdx.x * 64;
    const int k0 = blockIdx.z * 128;
    float acc[4][4] = {};
    mm_tile<false>(A, 512, W, 128, i0, j0, k0, k0 + 128, acc, As, Bs);
    const int tid = threadIdx.x;
    const int tx = tid & 15, ty = tid >> 4;
    float* dst = part + blockIdx.z * zstr;
#pragma unroll
    for (int u = 0; u < 4; ++u) {
        const size_t ri = (size_t)(by * 64 + ty * 4 + u) * 128 + j0 + tx * 4;
#pragma unroll
        for (int v = 0; v < 4; ++v) dst[ri + v] = acc[u][v];
    }
}

// ---------------- fp32 symmetric gram, triangular dual store ---------------
__launch_bounds__(256)
__global__ void gram_tri(const float* __restrict__ A, float* __restrict__ C, int n)
{
    __shared__ float As[16][68];
    __shared__ float Bs[16][68];
    __shared__ float Ts[64][68];
    const int b = blockIdx.x;
    int by = (int)((sqrtf(8.0f * b + 1.0f) - 1.0f) * 0.5f);
    while ((by + 1) * (by + 2) / 2 <= b) ++by;
    while (by * (by + 1) / 2 > b) --by;
    const int bx = b - by * (by + 1) / 2;
    const int i0 = by * 64, j0 = bx * 64;
    float acc[4][4] = {};
    mm_tile<true>(A, 128, A, 128, i0, j0, 0, 128, acc, As, Bs);
    const int tid = threadIdx.x;
    const int tx = tid & 15, ty = tid >> 4;
#pragma unroll
    for (int u = 0; u < 4; ++u) {
        const size_t ri = (size_t)(i0 + ty * 4 + u) * n + j0 + tx * 4;
#pragma unroll
        for (int v = 0; v < 4; ++v) {
            C[ri + v] = acc[u][v];
            Ts[tx * 4 + v][ty * 4 + u] = acc[u][v];
        }
    }
    if (bx == by) return;
    __syncthreads();
    const int r = tid >> 2;
    const int c0 = (tid & 3) * 16;
#pragma unroll
    for (int m = 0; m < 4; ++m) {
        float4 v = *(const float4*)&Ts[r][c0 + m * 4];
        *(float4*)(C + (size_t)(j0 + r) * n + i0 + c0 + m * 4) = v;
    }
}

// ---------------- universal bf16 MFMA GEMM ---------------------------------
// C[:, j0:j0+128] tile of 64 rows; A [M][lda] bf16 row-major (A[m][k]);
// B [N][ldb] bf16 row-major holding B^T i.e. Bmat[k][n] = B[n][k].
// z-dim: k0 = z*kZ, A += z*aZ, B += z*bZ, C += z*cZ  (covers split-K and
// batched-weight uses with one kernel).
__launch_bounds__(256)
__global__ void mm_bf16(const unsigned short* __restrict__ A, int lda, size_t aZ,
                        const unsigned short* __restrict__ B, int ldb, size_t bZ,
                        float* __restrict__ C, int ldc, size_t cZ,
                        int Kc, int kZ)
{
    __shared__ unsigned short As[64][40];
    __shared__ unsigned short Bs[128][40];
    const int tid = threadIdx.x;
    const int bz = blockIdx.z;
    const int i0 = blockIdx.y * 64;
    const int j0 = blockIdx.x * 128;
    const int k0 = bz * kZ;
    const unsigned short* Ab = A + (size_t)bz * aZ;
    const unsigned short* Bb = B + (size_t)bz * bZ;
    float* Cb = C + (size_t)bz * cZ;
    const int w = tid >> 6;
    const int lane = tid & 63;
    const int m = lane & 15;
    const int q = lane >> 4;
    f32x4 acc[8];
#pragma unroll
    for (int t = 0; t < 8; ++t)
#pragma unroll
        for (int r = 0; r < 4; ++r) acc[t][r] = 0.0f;

    const int ar = tid >> 2;        // 0..63
    const int ac = (tid & 3) * 8;   // 0,8,16,24
    for (int ks = 0; ks < Kc; ks += 32) {
        const int k = k0 + ks;
        *(ulonglong2*)&As[ar][ac] =
            *(const ulonglong2*)(Ab + (size_t)(i0 + ar) * lda + k + ac);
        *(ulonglong2*)&Bs[ar][ac] =
            *(const ulonglong2*)(Bb + (size_t)(j0 + ar) * ldb + k + ac);
        *(ulonglong2*)&Bs[ar + 64][ac] =
            *(const ulonglong2*)(Bb + (size_t)(j0 + ar + 64) * ldb + k + ac);
        __syncthreads();
        short8 a = *(const short8*)&As[w * 16 + m][q * 8];
#pragma unroll
        for (int nt = 0; nt < 8; ++nt) {
            short8 b = *(const short8*)&Bs[nt * 16 + m][q * 8];
            acc[nt] = __builtin_amdgcn_mfma_f32_16x16x32_bf16(a, b, acc[nt], 0, 0, 0);
        }
        __syncthreads();
    }
    // D: col = lane&15 (within 16-tile), row = q*4 + reg
#pragma unroll
    for (int nt = 0; nt < 8; ++nt) {
        const int col = j0 + nt * 16 + m;
#pragma unroll
        for (int r = 0; r < 4; ++r) {
            const int row = i0 + w * 16 + q * 4 + r;
            Cb[(size_t)row * ldc + col] = acc[nt][r];
        }
    }
}

// ---------------- combine partials + bias + l2norm -------------------------
__global__ void combine_norm(const float* __restrict__ part, int nz, size_t zstr,
                             const float* __restrict__ bias,
                             float* __restrict__ f32out,
                             unsigned short* __restrict__ bf16out)
{
    const int row = blockIdx.x;
    const int tid = threadIdx.x;                 // 128
    float v = bias[tid];
    for (int z = 0; z < nz; ++z) v += part[(size_t)z * zstr + (size_t)row * 128 + tid];
    __shared__ float red[128];
    red[tid] = v * v;
    __syncthreads();
    for (int s = 64; s > 0; s >>= 1) {
        if (tid < s) red[tid] += red[tid + s];
        __syncthreads();
    }
    float o = v * (1.0f / sqrtf(red[0]));
    if (f32out)  f32out[(size_t)row * 128 + tid] = o;
    if (bf16out) bf16out[(size_t)row * 128 + tid] = f2bf(o);
}

// ------------- threshold gram -> A01 bf16, pack bits, deg -> dinv ----------
__global__ void threshold_pack(const float* __restrict__ G,
                               unsigned short* __restrict__ A01,
                               unsigned long long* __restrict__ bits,
                               float* __restrict__ dinv)
{
    const int row = blockIdx.x;
    const int tid = threadIdx.x;
    const int lane = tid & 63;
    const int wave = tid >> 6;
    int total = 0;
    for (int c = 0; c < 8; ++c) {
        const int chunk = wave * 8 + c;
        const int j = chunk * 64 + lane;
        float g = G[(size_t)row * 2048 + j];
        bool a = (j == row) ? true : (g > 0.0f);
        unsigned long long mk = __ballot(a);
        A01[(size_t)row * 2048 + j] = a ? (unsigned short)0x3F80 : (unsigned short)0;
        if (lane == 0) bits[(size_t)row * 32 + chunk] = mk;
        total += __popcll(mk);
    }
    __shared__ int wred[4];
    if (lane == 0) wred[wave] = total;
    __syncthreads();
    if (tid == 0) {
        float deg = (float)(wred[0] + wred[1] + wred[2] + wred[3]);
        dinv[row] = 1.0f / sqrtf(deg);
    }
}

// ------------- Xt1[n][i] = f_e[(branch)i][n&127] * dinv[i]  (bf16) ---------
// grid (8, 64): bx = n-tile/32, by = i-tile/32.
__global__ void make_xt(const float* __restrict__ f_e, const float* __restrict__ dinv,
                        unsigned short* __restrict__ xt)
{
    __shared__ float T[32][33];
    const int tid = threadIdx.x;                 // 256
    const int iloc = tid >> 3, nq = (tid & 7) * 4;
    const int n0 = blockIdx.x * 32;
    const int i = blockIdx.y * 32 + iloc;
    const int srow = (n0 >= 128 ? 2048 : 0) + i;
    float4 f = *(const float4*)(f_e + (size_t)srow * 128 + ((n0 + nq) & 127));
    const float d = dinv[i];
    T[nq + 0][iloc] = f.x * d; T[nq + 1][iloc] = f.y * d;
    T[nq + 2][iloc] = f.z * d; T[nq + 3][iloc] = f.w * d;
    __syncthreads();
    const int nloc = tid >> 3, ic = (tid & 7) * 4;
    unsigned short o[4];
#pragma unroll
    for (int c = 0; c < 4; ++c) o[c] = f2bf(T[nloc][ic + c]);
    *(ulonglong1*)(xt + (size_t)(n0 + nloc) * 2048 + blockIdx.y * 32 + ic) =
        *(ulonglong1*)o;
}

// ------------- reduce hop partials -> hb bf16 (+ optional Xt-next) ---------
// part: nz x [M][256] fp32; hb[(branch*M+i)][n&127] = bf16(sum*dinv[i]);
// xt[n][i] = bf16(sum*dinv[i]^2). grid (8, M/32).
__global__ void reduce_hop(const float* __restrict__ part, int nz, size_t zstr,
                           int M, const float* __restrict__ dinv,
                           unsigned short* __restrict__ hb,
                           unsigned short* __restrict__ xt)
{
    __shared__ float T[32][33];
    const int tid = threadIdx.x;                 // 256
    const int iloc = tid >> 3, nq = (tid & 7) * 4;
    const int n = blockIdx.x * 32 + nq;
    const int i = blockIdx.y * 32 + iloc;
    float4 s = *(const float4*)(part + (size_t)i * 256 + n);
    for (int z = 1; z < nz; ++z) {
        float4 t = *(const float4*)(part + (size_t)z * zstr + (size_t)i * 256 + n);
        s.x += t.x; s.y += t.y; s.z += t.z; s.w += t.w;
    }
    const float d = dinv[i];
    unsigned short o[4] = { f2bf(s.x * d), f2bf(s.y * d), f2bf(s.z * d), f2bf(s.w * d) };
    const int hrow = (n >= 128 ? M : 0) + i;
    *(ulonglong1*)(hb + (size_t)hrow * 128 + (n & 127)) = *(ulonglong1*)o;
    if (xt) {
        const float d2 = d * d;
        T[nq + 0][iloc] = s.x * d2; T[nq + 1][iloc] = s.y * d2;
        T[nq + 2][iloc] = s.z * d2; T[nq + 3][iloc] = s.w * d2;
        __syncthreads();
        const int nloc = tid >> 3, ic = (tid & 7) * 4;
        unsigned short o2[4];
#pragma unroll
        for (int c = 0; c < 4; ++c) o2[c] = f2bf(T[nloc][ic + c]);
        *(ulonglong1*)(xt + (size_t)(blockIdx.x * 32 + nloc) * M + blockIdx.y * 32 + ic) =
            *(ulonglong1*)o2;
    }
}

// ------------- convert TAG weights to bf16 transposed ----------------------
// Wtall[c][n][k] = W_c[k][n].  c<3: W_gnn chunk c; c>=3: W_gnnp chunk c-3.
__global__ void convert_w(const float* __restrict__ Wg, const float* __restrict__ Wp,
                          unsigned short* __restrict__ Wtall)
{
    const int c = blockIdx.x, n = blockIdx.y, k = threadIdx.x;   // grid (5,128),128
    const float* src = (c < 3) ? (Wg + (size_t)c * 16384) : (Wp + (size_t)(c - 3) * 16384);
    Wtall[(size_t)c * 16384 + n * 128 + k] = f2bf(src[(size_t)k * 128 + n]);
}

// ------------- NCE rows: z=0 -> G1, z=1 -> G2 ------------------------------
__global__ void nce_rows(const float* __restrict__ G1, const float* __restrict__ G2,
                         int n, float invN, float* __restrict__ out)
{
    const float* G = blockIdx.y ? G2 : G1;
    const int row = blockIdx.x;
    const int tid = threadIdx.x;
    const float pos = G[(size_t)row * n + row];
    float m = pos;
    for (int j = tid; j < n; j += 256) {
        float g = (j == row) ? NEGF : G[(size_t)row * n + j];
        m = fmaxf(m, g);
    }
    __shared__ float red[256];
    red[tid] = m;
    __syncthreads();
    for (int s = 128; s > 0; s >>= 1) {
        if (tid < s) red[tid] = fmaxf(red[tid], red[tid + s]);
        __syncthreads();
    }
    m = red[0];
    __syncthreads();
    float ssum = (tid == 0) ? expf((pos - m) * TINV) : 0.0f;
    for (int j = tid; j < n; j += 256) {
        float g = (j == row) ? NEGF : G[(size_t)row * n + j];
        ssum += expf((g - m) * TINV);
    }
    red[tid] = ssum;
    __syncthreads();
    for (int s = 128; s > 0; s >>= 1) {
        if (tid < s) red[tid] += red[tid + s];
        __syncthreads();
    }
    if (tid == 0)
        atomicAdd(out, (logf(red[0]) + (m - pos) * TINV) * invN);
}

// ------------- pooling score ----------------------------------------------
__global__ void pool_score(const float* __restrict__ f, const float* __restrict__ Wp,
                           const float* __restrict__ bp, float* __restrict__ scores)
{
    const int row = blockIdx.x;
    const int tid = threadIdx.x;                 // 128
    float v = f[(size_t)row * 128 + tid] * Wp[tid];
    __shared__ float red[128];
    red[tid] = v;
    __syncthreads();
    for (int s = 64; s > 0; s >>= 1) {
        if (tid < s) red[tid] += red[tid + s];
        __syncthreads();
    }
    if (tid == 0) scores[row] = 1.0f / (1.0f + expf(-(red[0] + bp[0])));
}

// ------------- top-1024 of 2048 via radix select (1 block, 1024 thr) -------
// Output order is irrelevant downstream (loss is row-permutation invariant);
// tie-break at the cut = smallest index (matches lax.top_k membership).
__global__ void topk_radix(const float* __restrict__ scores,
                           float* __restrict__ vals, int* __restrict__ idx)
{
    __shared__ unsigned sv[2048];
    __shared__ int hist[256];
    __shared__ int sh_prefix, sh_remain, sh_wsum[17], sh_out;
    const int tid = threadIdx.x;                 // 1024
    sv[tid] = __float_as_uint(scores[tid]);
    sv[tid + 1024] = __float_as_uint(scores[tid + 1024]);
    if (tid == 0) { sh_prefix = 0; sh_remain = 1024; sh_out = 0; }
    __syncthreads();
    for (int byte = 3; byte >= 0; --byte) {
        if (tid < 256) hist[tid] = 0;
        __syncthreads();
        const unsigned pref = (unsigned)sh_prefix;
        const unsigned pmask = (byte == 3) ? 0u : (0xFFFFFFFFu << ((byte + 1) * 8));
        for (int e = tid; e < 2048; e += 1024) {
            unsigned u = sv[e];
            if ((u & pmask) == (pref & pmask))
                atomicAdd(&hist[(u >> (byte * 8)) & 255], 1);
        }
        __syncthreads();
        if (tid == 0) {
            int rem = sh_remain, b = 255;
            for (; b > 0; --b) {
                if (hist[b] >= rem) break;
                rem -= hist[b];
            }
            sh_prefix = (int)(pref | ((unsigned)b << (byte * 8)));
            sh_remain = rem;
        }
        __syncthreads();
    }
    const unsigned t = (unsigned)sh_prefix;
    const int remain = sh_remain;                // # of ==t to take (by index)
    const int wave = tid >> 6, lane = tid & 63;
    int rank[2];
    int base = 0;
    for (int pass = 0; pass < 2; ++pass) {
        const int e = pass * 1024 + tid;
        const bool eq = (sv[e] == t);
        unsigned long long mk = __ballot(eq);
        int wpre = __popcll(mk & ((1ull << lane) - 1ull));
        if (lane == 0) sh_wsum[wave] = __popcll(mk);
        __syncthreads();
        if (tid == 0) {
            int a = base;
            for (int w = 0; w < 16; ++w) { int c = sh_wsum[w]; sh_wsum[w] = a; a += c; }
            sh_wsum[16] = a;
        }
        __syncthreads();
        rank[pass] = eq ? (sh_wsum[wave] + wpre) : 0x7fffffff;
        base = sh_wsum[16];
        __syncthreads();
    }
    for (int pass = 0; pass < 2; ++pass) {
        const int e = pass * 1024 + tid;
        const unsigned u = sv[e];
        const bool sel = (u > t) || (u == t && rank[pass] < remain);
        if (sel) {
            int slot = atomicAdd(&sh_out, 1);
            idx[slot] = e;
            vals[slot] = __uint_as_float(u);
        }
    }
}

// ------------- gather pooled features + build Xtp --------------------------
// new_hb[(branch*1024+p)][n&127] = bf16(f_g[sel][n]*val);
// Xtp[n][p] = bf16(same * dinvp[p]). grid (8, 32).
__global__ void gather_xt(const float* __restrict__ f_g, const int* __restrict__ idx,
                          const float* __restrict__ vals, const float* __restrict__ dinvp,
                          unsigned short* __restrict__ new_hb,
                          unsigned short* __restrict__ xtp)
{
    __shared__ float T[32][33];
    const int tid = threadIdx.x;                 // 256
    const int ploc = tid >> 3, nq = (tid & 7) * 4;
    const int n0 = blockIdx.x * 32;
    const int p = blockIdx.y * 32 + ploc;
    const int s = idx[p];
    const float v = vals[p];
    const float dp = dinvp[p];
    const int srow = (n0 >= 128 ? 2048 : 0) + s;
    float4 f = *(const float4*)(f_g + (size_t)srow * 128 + ((n0 + nq) & 127));
    f.x *= v; f.y *= v; f.z *= v; f.w *= v;
    unsigned short o[4] = { f2bf(f.x), f2bf(f.y), f2bf(f.z), f2bf(f.w) };
    const int hrow = (n0 >= 128 ? 1024 : 0) + p;
    *(ulonglong1*)(new_hb + (size_t)hrow * 128 + ((n0 + nq) & 127)) = *(ulonglong1*)o;
    T[nq + 0][ploc] = f.x * dp; T[nq + 1][ploc] = f.y * dp;
    T[nq + 2][ploc] = f.z * dp; T[nq + 3][ploc] = f.w * dp;
    __syncthreads();
    const int nloc = tid >> 3, pc = (tid & 7) * 4;
    unsigned short o2[4];
#pragma unroll
    for (int c = 0; c < 4; ++c) o2[c] = f2bf(T[nloc][pc + c]);
    *(ulonglong1*)(xtp + (size_t)(n0 + nloc) * 1024 + blockIdx.y * 32 + pc) =
        *(ulonglong1*)o2;
}

// ------------- Ap01 bf16 from packed bits ----------------------------------
__global__ void build_ap(const unsigned long long* __restrict__ bits,
                         const int* __restrict__ idx, unsigned short* __restrict__ Ap)
{
    __shared__ unsigned long long pb[16][32];
    __shared__ unsigned long long qb[16][32];
    const int tp = blockIdx.y * 16;
    const int tq = blockIdx.x * 16;
    const int tid = threadIdx.x;                 // 256
    for (int t = tid; t < 512; t += 256) {
        int r = t >> 5, w = t & 31;
        pb[r][w] = bits[(size_t)idx[tp + r] * 32 + w];
        qb[r][w] = bits[(size_t)idx[tq + r] * 32 + w];
    }
    __syncthreads();
    const int pi = tid >> 4, qi = tid & 15;
    unsigned long long acc = 0;
#pragma unroll
    for (int w = 0; w < 32; ++w) acc |= (pb[pi][w] & qb[qi][w]);
    Ap[(size_t)(tp + pi) * 1024 + tq + qi] = acc ? (unsigned short)0x3F80 : (unsigned short)0;
}

// ------------- rowsum of 0/1 bf16 -> 1/sqrt(deg) ---------------------------
__global__ void rowsum_rsqrt(const unsigned short* __restrict__ Ap,
                             float* __restrict__ dinvp, int n)
{
    const int row = blockIdx.x;
    const int tid = threadIdx.x;                 // 256
    int s = 0;
    for (int j = tid; j < n; j += 256) s += (Ap[(size_t)row * n + j] != 0);
    __shared__ int red[256];
    red[tid] = s;
    __syncthreads();
    for (int st = 128; st > 0; st >>= 1) {
        if (tid < st) red[tid] += red[tid + st];
        __syncthreads();
    }
    if (tid == 0) dinvp[row] = 1.0f / sqrtf((float)red[0]);
}

__global__ void zero1(float* __restrict__ p) { p[0] = 0.0f; }

// ---------------------------------------------------------------------------
extern "C" void kernel_launch(void* const* d_in, const int* in_sizes, int n_in,
                              void* d_out, int out_size, void* d_ws, size_t ws_size,
                              hipStream_t stream)
{
    (void)in_sizes; (void)n_in; (void)out_size; (void)ws_size;
    const float* fs      = (const float*)d_in[0];
    const float* ft      = (const float*)d_in[1];
    const float* W_embed = (const float*)d_in[2];
    const float* b_embed = (const float*)d_in[3];
    const float* W_gnn   = (const float*)d_in[4];
    const float* b_gnn   = (const float*)d_in[5];
    const float* W_pool  = (const float*)d_in[6];
    const float* b_pool  = (const float*)d_in[7];
    const float* W_gnnp  = (const float*)d_in[8];
    const float* b_gnnp  = (const float*)d_in[9];
    float* out = (float*)d_out;

    float* ws = (float*)d_ws;
    size_t o = 0;
    auto alloc = [&](size_t n) { float* p = ws + o; o += (n + 3) & ~3ull; return p; };
    float* bigA   = alloc(2048ull * 2048);       // S -> G1
    float* bigB   = alloc(2048ull * 2048);       // partials / G2 / pooled
    float* f_e    = alloc(4096 * 128);           // fp32 embed (t rows 0.., s rows 2048..)
    float* f_g    = alloc(4096 * 128);           // fp32 f_gt/f_gs
    unsigned short* A01  = (unsigned short*)alloc(2048ull * 2048 / 2);
    unsigned short* febT = (unsigned short*)alloc(3ull * 4096 * 128 / 2); // feb,h1b,h2b
    unsigned short* Xt1  = (unsigned short*)alloc(256ull * 2048 / 2);
    unsigned short* Xt2  = (unsigned short*)alloc(256ull * 2048 / 2);
    unsigned short* f_gb = (unsigned short*)alloc(4096ull * 128 / 2);
    unsigned short* Wtall= (unsigned short*)alloc(5ull * 16384 / 2);
    unsigned short* Ap01 = (unsigned short*)alloc(1024ull * 1024 / 2);
    unsigned short* nhb  = (unsigned short*)alloc(2ull * 2048 * 128 / 2); // new_hb,tmpb
    unsigned short* Xtp  = (unsigned short*)alloc(256ull * 1024 / 2);
    unsigned short* f_pb = (unsigned short*)alloc(2048ull * 128 / 2);
    float* dinv   = alloc(2048);
    float* scores = alloc(2048);
    float* vals   = alloc(1024);
    int*   idxb   = (int*)alloc(1024);
    float* dinvp  = alloc(1024);
    unsigned long long* bits = (unsigned long long*)alloc(2048 * 32 * 2);

    const size_t FSTR = 4096ull * 128;           // 524288: embed/tag/hop partial stride
    const size_t PSTR = 1024ull * 256;           // 262144: pooled partial stride
    unsigned short* feb = febT;
    unsigned short* h1b = febT + FSTR;
    unsigned short* h2b = febT + 2 * FSTR;
    unsigned short* Wt  = Wtall;                 // 3 chunks
    unsigned short* WtP = Wtall + 3ull * 16384;  // 2 chunks
    unsigned short* tmpb = nhb + 2048ull * 128;
    float* partP  = bigB;                        // pooled hop partials (8 x 1 MB)
    float* partTP = bigB + 8ull * PSTR;          // pooled tag partials (2 x 0.5 M)
    float* Gp1    = bigB;                        // after partP consumed
    float* Gp2    = bigB + 1024ull * 1024;

    zero1<<<1, 1, 0, stream>>>(out);
    convert_w<<<dim3(5, 128), 128, 0, stream>>>(W_gnn, W_gnnp, Wtall);

    // ---- embed (fp32, merged) + l2norm ----
    gemm_embed<<<dim3(2, 64, 4), 256, 0, stream>>>(fs, ft, W_embed, bigB, FSTR);
    combine_norm<<<4096, 128, 0, stream>>>(bigB, 4, FSTR, b_embed, f_e, feb);

    // ---- adjacency: fp32 gram (exact threshold), A01 bf16 + bits + dinv ----
    gram_tri<<<528, 256, 0, stream>>>(f_e, bigA, 2048);   // teacher rows = f_e[0:2048]
    threshold_pack<<<2048, 256, 0, stream>>>(bigA, A01, bits, dinv);
    make_xt<<<dim3(8, 64), 256, 0, stream>>>(f_e, dinv, Xt1);

    // ---- hop1/hop2 (bf16 MFMA, teacher+student N=256, split-K 8) ----
    mm_bf16<<<dim3(2, 32, 8), 256, 0, stream>>>(A01, 2048, 0, Xt1, 2048, 0,
                                                bigB, 256, FSTR, 256, 256);
    reduce_hop<<<dim3(8, 64), 256, 0, stream>>>(bigB, 8, FSTR, 2048, dinv, h1b, Xt2);
    mm_bf16<<<dim3(2, 32, 8), 256, 0, stream>>>(A01, 2048, 0, Xt2, 2048, 0,
                                                bigB, 256, FSTR, 256, 256);
    reduce_hop<<<dim3(8, 64), 256, 0, stream>>>(bigB, 8, FSTR, 2048, dinv, h2b, nullptr);

    // ---- TAG linear (batched z=3 over hop terms, M=4096) + l2norm ----
    mm_bf16<<<dim3(1, 64, 3), 256, 0, stream>>>(feb, 128, FSTR, Wt, 128, 16384,
                                                bigB, 128, FSTR, 128, 0);
    combine_norm<<<4096, 128, 0, stream>>>(bigB, 3, FSTR, b_gnn, f_g, f_gb);

    // ---- graph NCE: two bf16 grams + fused row-LSE ----
    mm_bf16<<<dim3(16, 32, 1), 256, 0, stream>>>(f_gb, 128, 0, f_gb + 2048 * 128, 128, 0,
                                                 bigA, 2048, 0, 128, 0);
    mm_bf16<<<dim3(16, 32, 1), 256, 0, stream>>>(f_gb + 2048 * 128, 128, 0, f_gb, 128, 0,
                                                 bigB, 2048, 0, 128, 0);
    nce_rows<<<dim3(2048, 2), 256, 0, stream>>>(bigA, bigB, 2048, 1.0f / 2048.0f, out);

    // ---- pooling ----
    pool_score<<<2048, 128, 0, stream>>>(f_g, W_pool, b_pool, scores);
    topk_radix<<<1, 1024, 0, stream>>>(scores, vals, idxb);
    build_ap<<<dim3(64, 64), 256, 0, stream>>>(bits, idxb, Ap01);
    rowsum_rsqrt<<<1024, 256, 0, stream>>>(Ap01, dinvp, 1024);
    gather_xt<<<dim3(8, 32), 256, 0, stream>>>(f_g, idxb, vals, dinvp, nhb, Xtp);

    // ---- pooled hop (bf16 MFMA, split-K 8) ----
    mm_bf16<<<dim3(2, 16, 8), 256, 0, stream>>>(Ap01, 1024, 0, Xtp, 1024, 0,
                                                partP, 256, PSTR, 128, 128);
    reduce_hop<<<dim3(8, 32), 256, 0, stream>>>(partP, 8, PSTR, 1024, dinvp, tmpb, nullptr);

    // ---- pooled TAG linear (z=2, M=2048) + l2norm (bf16 out only) ----
    mm_bf16<<<dim3(1, 32, 2), 256, 0, stream>>>(nhb, 128, 2048ull * 128, WtP, 128, 16384,
                                                partTP, 128, PSTR, 128, 0);
    combine_norm<<<2048, 128, 0, stream>>>(partTP, 2, PSTR, b_gnnp, nullptr, f_pb);

    // ---- pooled NCE ----
    mm_bf16<<<dim3(8, 16, 1), 256, 0, stream>>>(f_pb, 128, 0, f_pb + 1024 * 128, 128, 0,
                                                Gp1, 1024, 0, 128, 0);
    mm_bf16<<<dim3(8, 16, 1), 256, 0, stream>>>(f_pb + 1024 * 128, 128, 0, f_pb, 128, 0,
                                                Gp2, 1024, 0, 128, 0);
    nce_rows<<<dim3(1024, 2), 256, 0, stream>>>(Gp1, Gp2, 1024, 1.0f / 1024.0f, out);
}

// Round 4
// 268.445 us; speedup vs baseline: 4.0444x; 1.3544x over previous
//
#include <hip/hip_runtime.h>

// ---------------------------------------------------------------------------
// GNNLoss. N=2048, C=512, D=128, K_POOL=1024, T=0.07, NEG=-10.
// Round 4: NCE fused into gram epilogue (row/col exp-sums, no max shift, no
// gram materialization, second gram = column sums). bf16 MFMA everywhere
// except embed + adjacency gram (discrete threshold -> fp32).
// ---------------------------------------------------------------------------

#define TINV (1.0f / 0.07f)
#define NEGF (-10.0f)

using short8 = __attribute__((ext_vector_type(8))) short;
using f32x4  = __attribute__((ext_vector_type(4))) float;

__device__ __forceinline__ unsigned short f2bf(float f) {
    unsigned u = __float_as_uint(f);
    u += 0x7fff + ((u >> 16) & 1);
    return (unsigned short)(u >> 16);
}

// ---------------- fp32 64x64 tile core (round-2, verified) -----------------
template<bool BT>
__device__ __forceinline__ void mm_tile(const float* __restrict__ A, int lda,
                                        const float* __restrict__ B, int ldb,
                                        int i0, int j0, int k0, int k1,
                                        float (&acc)[4][4],
                                        float (&As)[16][68], float (&Bs)[16][68])
{
    const int tid = threadIdx.x;
    const int tx = tid & 15;
    const int ty = tid >> 4;
    const int lr = tid >> 2;
    const int lc = (tid & 3) * 4;
    for (int k = k0; k < k1; k += 16) {
        float4 av = *(const float4*)(A + (size_t)(i0 + lr) * lda + (k + lc));
        As[lc + 0][lr] = av.x; As[lc + 1][lr] = av.y;
        As[lc + 2][lr] = av.z; As[lc + 3][lr] = av.w;
        if (BT) {
            float4 bv = *(const float4*)(B + (size_t)(j0 + lr) * ldb + (k + lc));
            Bs[lc + 0][lr] = bv.x; Bs[lc + 1][lr] = bv.y;
            Bs[lc + 2][lr] = bv.z; Bs[lc + 3][lr] = bv.w;
        } else {
            const int n = tid & 63;
            const int kb = tid >> 6;
#pragma unroll
            for (int it = 0; it < 4; ++it)
                Bs[kb * 4 + it][n] = B[(size_t)(k + kb * 4 + it) * ldb + (j0 + n)];
        }
        __syncthreads();
#pragma unroll
        for (int kk = 0; kk < 16; ++kk) {
            float a[4], b[4];
#pragma unroll
            for (int u = 0; u < 4; ++u) a[u] = As[kk][ty * 4 + u];
#pragma unroll
            for (int v = 0; v < 4; ++v) b[v] = Bs[kk][tx * 4 + v];
#pragma unroll
            for (int u = 0; u < 4; ++u)
#pragma unroll
                for (int v = 0; v < 4; ++v)
                    acc[u][v] = fmaf(a[u], b[v], acc[u][v]);
        }
        __syncthreads();
    }
}

// ---------------- fp32 embed GEMM, teacher+student merged ------------------
__launch_bounds__(256)
__global__ void gemm_embed(const float* __restrict__ fs, const float* __restrict__ ft,
                           const float* __restrict__ W, float* __restrict__ part,
                           size_t zstr)
{
    __shared__ float As[16][68];
    __shared__ float Bs[16][68];
    const int by = blockIdx.y;
    const float* A = (by < 32) ? ft : fs;
    const int i0 = (by < 32) ? by * 64 : (by - 32) * 64;
    const int j0 = blockIdx.x * 64;
    const int k0 = blockIdx.z * 128;
    float acc[4][4] = {};
    mm_tile<false>(A, 512, W, 128, i0, j0, k0, k0 + 128, acc, As, Bs);
    const int tid = threadIdx.x;
    const int tx = tid & 15, ty = tid >> 4;
    float* dst = part + blockIdx.z * zstr;
#pragma unroll
    for (int u = 0; u < 4; ++u) {
        const size_t ri = (size_t)(by * 64 + ty * 4 + u) * 128 + j0 + tx * 4;
#pragma unroll
        for (int v = 0; v < 4; ++v) dst[ri + v] = acc[u][v];
    }
}

// ---------------- fp32 symmetric gram, triangular dual store ---------------
__launch_bounds__(256)
__global__ void gram_tri(const float* __restrict__ A, float* __restrict__ C, int n)
{
    __shared__ float As[16][68];
    __shared__ float Bs[16][68];
    __shared__ float Ts[64][68];
    const int b = blockIdx.x;
    int by = (int)((sqrtf(8.0f * b + 1.0f) - 1.0f) * 0.5f);
    while ((by + 1) * (by + 2) / 2 <= b) ++by;
    while (by * (by + 1) / 2 > b) --by;
    const int bx = b - by * (by + 1) / 2;
    const int i0 = by * 64, j0 = bx * 64;
    float acc[4][4] = {};
    mm_tile<true>(A, 128, A, 128, i0, j0, 0, 128, acc, As, Bs);
    const int tid = threadIdx.x;
    const int tx = tid & 15, ty = tid >> 4;
#pragma unroll
    for (int u = 0; u < 4; ++u) {
        const size_t ri = (size_t)(i0 + ty * 4 + u) * n + j0 + tx * 4;
#pragma unroll
        for (int v = 0; v < 4; ++v) {
            C[ri + v] = acc[u][v];
            Ts[tx * 4 + v][ty * 4 + u] = acc[u][v];
        }
    }
    if (bx == by) return;
    __syncthreads();
    const int r = tid >> 2;
    const int c0 = (tid & 3) * 16;
#pragma unroll
    for (int m = 0; m < 4; ++m) {
        float4 v = *(const float4*)&Ts[r][c0 + m * 4];
        *(float4*)(C + (size_t)(j0 + r) * n + i0 + c0 + m * 4) = v;
    }
}

// ---------------- universal bf16 MFMA GEMM (stores C) ----------------------
__launch_bounds__(256)
__global__ void mm_bf16(const unsigned short* __restrict__ A, int lda, size_t aZ,
                        const unsigned short* __restrict__ B, int ldb, size_t bZ,
                        float* __restrict__ C, int ldc, size_t cZ,
                        int Kc, int kZ)
{
    __shared__ unsigned short As[64][40];
    __shared__ unsigned short Bs[128][40];
    const int tid = threadIdx.x;
    const int bz = blockIdx.z;
    const int i0 = blockIdx.y * 64;
    const int j0 = blockIdx.x * 128;
    const int k0 = bz * kZ;
    const unsigned short* Ab = A + (size_t)bz * aZ;
    const unsigned short* Bb = B + (size_t)bz * bZ;
    float* Cb = C + (size_t)bz * cZ;
    const int w = tid >> 6;
    const int lane = tid & 63;
    const int m = lane & 15;
    const int q = lane >> 4;
    f32x4 acc[8];
#pragma unroll
    for (int t = 0; t < 8; ++t)
#pragma unroll
        for (int r = 0; r < 4; ++r) acc[t][r] = 0.0f;

    const int ar = tid >> 2;
    const int ac = (tid & 3) * 8;
    for (int ks = 0; ks < Kc; ks += 32) {
        const int k = k0 + ks;
        *(ulonglong2*)&As[ar][ac] =
            *(const ulonglong2*)(Ab + (size_t)(i0 + ar) * lda + k + ac);
        *(ulonglong2*)&Bs[ar][ac] =
            *(const ulonglong2*)(Bb + (size_t)(j0 + ar) * ldb + k + ac);
        *(ulonglong2*)&Bs[ar + 64][ac] =
            *(const ulonglong2*)(Bb + (size_t)(j0 + ar + 64) * ldb + k + ac);
        __syncthreads();
        short8 a = *(const short8*)&As[w * 16 + m][q * 8];
#pragma unroll
        for (int nt = 0; nt < 8; ++nt) {
            short8 b = *(const short8*)&Bs[nt * 16 + m][q * 8];
            acc[nt] = __builtin_amdgcn_mfma_f32_16x16x32_bf16(a, b, acc[nt], 0, 0, 0);
        }
        __syncthreads();
    }
#pragma unroll
    for (int nt = 0; nt < 8; ++nt) {
        const int col = j0 + nt * 16 + m;
#pragma unroll
        for (int r = 0; r < 4; ++r) {
            const int row = i0 + w * 16 + q * 4 + r;
            Cb[(size_t)row * ldc + col] = acc[nt][r];
        }
    }
}

// ---------------- fused gram + NCE partial sums ----------------------------
// G = A @ B^T (A,B: [n][128] bf16, l2-normalized rows => |G|<=1).
// rowsum[i] += sum_{j!=i} exp(G_ij/T); colsum[j] += sum_{i!=j} exp(G_ij/T);
// pos[i] = G_ii. No max shift needed (|G|/T <= 14.3). grid (n/128, n/64).
__launch_bounds__(256)
__global__ void gram_nce(const unsigned short* __restrict__ A,
                         const unsigned short* __restrict__ B,
                         float* __restrict__ rowsum, float* __restrict__ colsum,
                         float* __restrict__ pos)
{
    __shared__ unsigned short As[64][40];
    __shared__ unsigned short Bs[128][40];
    __shared__ float colbuf[4][128];
    const int tid = threadIdx.x;
    const int i0 = blockIdx.y * 64;
    const int j0 = blockIdx.x * 128;
    const int w = tid >> 6;
    const int lane = tid & 63;
    const int m = lane & 15;
    const int q = lane >> 4;
    f32x4 acc[8];
#pragma unroll
    for (int t = 0; t < 8; ++t)
#pragma unroll
        for (int r = 0; r < 4; ++r) acc[t][r] = 0.0f;

    const int ar = tid >> 2;
    const int ac = (tid & 3) * 8;
    for (int k = 0; k < 128; k += 32) {
        *(ulonglong2*)&As[ar][ac] =
            *(const ulonglong2*)(A + (size_t)(i0 + ar) * 128 + k + ac);
        *(ulonglong2*)&Bs[ar][ac] =
            *(const ulonglong2*)(B + (size_t)(j0 + ar) * 128 + k + ac);
        *(ulonglong2*)&Bs[ar + 64][ac] =
            *(const ulonglong2*)(B + (size_t)(j0 + ar + 64) * 128 + k + ac);
        __syncthreads();
        short8 a = *(const short8*)&As[w * 16 + m][q * 8];
#pragma unroll
        for (int nt = 0; nt < 8; ++nt) {
            short8 b = *(const short8*)&Bs[nt * 16 + m][q * 8];
            acc[nt] = __builtin_amdgcn_mfma_f32_16x16x32_bf16(a, b, acc[nt], 0, 0, 0);
        }
        __syncthreads();
    }
    // epilogue: exp + row/col partial reductions (D: row=q*4+r, col=nt*16+m)
    float rpart[4] = {0.0f, 0.0f, 0.0f, 0.0f};
    float cpart[8];
#pragma unroll
    for (int nt = 0; nt < 8; ++nt) {
        const int col = j0 + nt * 16 + m;
        float cs = 0.0f;
#pragma unroll
        for (int r = 0; r < 4; ++r) {
            const int row = i0 + w * 16 + q * 4 + r;
            float g = acc[nt][r];
            float e = __expf(g * TINV);
            if (row == col) { pos[row] = g; e = 0.0f; }
            rpart[r] += e;
            cs += e;
        }
        cpart[nt] = cs;
    }
#pragma unroll
    for (int r = 0; r < 4; ++r) {
        float v = rpart[r];
        v += __shfl_xor(v, 1); v += __shfl_xor(v, 2);
        v += __shfl_xor(v, 4); v += __shfl_xor(v, 8);
        if (m == 0) atomicAdd(&rowsum[i0 + w * 16 + q * 4 + r], v);
    }
#pragma unroll
    for (int nt = 0; nt < 8; ++nt) {
        float v = cpart[nt];
        v += __shfl_xor(v, 16); v += __shfl_xor(v, 32);
        if (q == 0) colbuf[w][nt * 16 + m] = v;
    }
    __syncthreads();
    if (tid < 128) {
        float v = colbuf[0][tid] + colbuf[1][tid] + colbuf[2][tid] + colbuf[3][tid];
        atomicAdd(&colsum[j0 + tid], v);
    }
}

// ---------------- NCE finalize: mean over rows ----------------------------
__global__ void nce_final(const float* __restrict__ rs, const float* __restrict__ cs,
                          const float* __restrict__ pos, int n, float invN,
                          float* __restrict__ out)
{
    const int i = blockIdx.x * 256 + threadIdx.x;
    float t = 0.0f;
    if (i < n) {
        float p = pos[i] * TINV;
        float ep = __expf(p);
        t = (logf(rs[i] + ep) - p) + (logf(cs[i] + ep) - p);
    }
    __shared__ float red[256];
    red[threadIdx.x] = t;
    __syncthreads();
    for (int s = 128; s > 0; s >>= 1) {
        if (threadIdx.x < s) red[threadIdx.x] += red[threadIdx.x + s];
        __syncthreads();
    }
    if (threadIdx.x == 0) atomicAdd(out, red[0] * invN);
}

// ---------------- combine partials + bias + l2norm -------------------------
__global__ void combine_norm(const float* __restrict__ part, int nz, size_t zstr,
                             const float* __restrict__ bias,
                             float* __restrict__ f32out,
                             unsigned short* __restrict__ bf16out)
{
    const int row = blockIdx.x;
    const int tid = threadIdx.x;                 // 128
    float v = bias[tid];
    for (int z = 0; z < nz; ++z) v += part[(size_t)z * zstr + (size_t)row * 128 + tid];
    __shared__ float red[128];
    red[tid] = v * v;
    __syncthreads();
    for (int s = 64; s > 0; s >>= 1) {
        if (tid < s) red[tid] += red[tid + s];
        __syncthreads();
    }
    float o = v * (1.0f / sqrtf(red[0]));
    if (f32out)  f32out[(size_t)row * 128 + tid] = o;
    if (bf16out) bf16out[(size_t)row * 128 + tid] = f2bf(o);
}

// ------------- threshold gram -> A01 bf16, pack bits, deg -> dinv ----------
__global__ void threshold_pack(const float* __restrict__ G,
                               unsigned short* __restrict__ A01,
                               unsigned long long* __restrict__ bits,
                               float* __restrict__ dinv)
{
    const int row = blockIdx.x;
    const int tid = threadIdx.x;
    const int lane = tid & 63;
    const int wave = tid >> 6;
    int total = 0;
    for (int c = 0; c < 8; ++c) {
        const int chunk = wave * 8 + c;
        const int j = chunk * 64 + lane;
        float g = G[(size_t)row * 2048 + j];
        bool a = (j == row) ? true : (g > 0.0f);
        unsigned long long mk = __ballot(a);
        A01[(size_t)row * 2048 + j] = a ? (unsigned short)0x3F80 : (unsigned short)0;
        if (lane == 0) bits[(size_t)row * 32 + chunk] = mk;
        total += __popcll(mk);
    }
    __shared__ int wred[4];
    if (lane == 0) wred[wave] = total;
    __syncthreads();
    if (tid == 0) {
        float deg = (float)(wred[0] + wred[1] + wred[2] + wred[3]);
        dinv[row] = 1.0f / sqrtf(deg);
    }
}

// ------------- Xt1[n][i] = f_e[(branch)i][n&127] * dinv[i]  (bf16) ---------
__global__ void make_xt(const float* __restrict__ f_e, const float* __restrict__ dinv,
                        unsigned short* __restrict__ xt)
{
    __shared__ float T[32][33];
    const int tid = threadIdx.x;                 // 256
    const int iloc = tid >> 3, nq = (tid & 7) * 4;
    const int n0 = blockIdx.x * 32;
    const int i = blockIdx.y * 32 + iloc;
    const int srow = (n0 >= 128 ? 2048 : 0) + i;
    float4 f = *(const float4*)(f_e + (size_t)srow * 128 + ((n0 + nq) & 127));
    const float d = dinv[i];
    T[nq + 0][iloc] = f.x * d; T[nq + 1][iloc] = f.y * d;
    T[nq + 2][iloc] = f.z * d; T[nq + 3][iloc] = f.w * d;
    __syncthreads();
    const int nloc = tid >> 3, ic = (tid & 7) * 4;
    unsigned short o[4];
#pragma unroll
    for (int c = 0; c < 4; ++c) o[c] = f2bf(T[nloc][ic + c]);
    *(ulonglong1*)(xt + (size_t)(n0 + nloc) * 2048 + blockIdx.y * 32 + ic) =
        *(ulonglong1*)o;
}

// ------------- reduce hop partials -> hb bf16 (+ optional Xt-next) ---------
__global__ void reduce_hop(const float* __restrict__ part, int nz, size_t zstr,
                           int M, const float* __restrict__ dinv,
                           unsigned short* __restrict__ hb,
                           unsigned short* __restrict__ xt)
{
    __shared__ float T[32][33];
    const int tid = threadIdx.x;                 // 256
    const int iloc = tid >> 3, nq = (tid & 7) * 4;
    const int n = blockIdx.x * 32 + nq;
    const int i = blockIdx.y * 32 + iloc;
    float4 s = *(const float4*)(part + (size_t)i * 256 + n);
    for (int z = 1; z < nz; ++z) {
        float4 t = *(const float4*)(part + (size_t)z * zstr + (size_t)i * 256 + n);
        s.x += t.x; s.y += t.y; s.z += t.z; s.w += t.w;
    }
    const float d = dinv[i];
    unsigned short o[4] = { f2bf(s.x * d), f2bf(s.y * d), f2bf(s.z * d), f2bf(s.w * d) };
    const int hrow = (n >= 128 ? M : 0) + i;
    *(ulonglong1*)(hb + (size_t)hrow * 128 + (n & 127)) = *(ulonglong1*)o;
    if (xt) {
        const float d2 = d * d;
        T[nq + 0][iloc] = s.x * d2; T[nq + 1][iloc] = s.y * d2;
        T[nq + 2][iloc] = s.z * d2; T[nq + 3][iloc] = s.w * d2;
        __syncthreads();
        const int nloc = tid >> 3, ic = (tid & 7) * 4;
        unsigned short o2[4];
#pragma unroll
        for (int c = 0; c < 4; ++c) o2[c] = f2bf(T[nloc][ic + c]);
        *(ulonglong1*)(xt + (size_t)(blockIdx.x * 32 + nloc) * M + blockIdx.y * 32 + ic) =
            *(ulonglong1*)o2;
    }
}

// ------------- convert TAG weights to bf16 transposed ----------------------
__global__ void convert_w(const float* __restrict__ Wg, const float* __restrict__ Wp,
                          unsigned short* __restrict__ Wtall)
{
    const int c = blockIdx.x, n = blockIdx.y, k = threadIdx.x;   // grid (5,128),128
    const float* src = (c < 3) ? (Wg + (size_t)c * 16384) : (Wp + (size_t)(c - 3) * 16384);
    Wtall[(size_t)c * 16384 + n * 128 + k] = f2bf(src[(size_t)k * 128 + n]);
}

// ------------- pooling score ----------------------------------------------
__global__ void pool_score(const float* __restrict__ f, const float* __restrict__ Wp,
                           const float* __restrict__ bp, float* __restrict__ scores)
{
    const int row = blockIdx.x;
    const int tid = threadIdx.x;                 // 128
    float v = f[(size_t)row * 128 + tid] * Wp[tid];
    __shared__ float red[128];
    red[tid] = v;
    __syncthreads();
    for (int s = 64; s > 0; s >>= 1) {
        if (tid < s) red[tid] += red[tid + s];
        __syncthreads();
    }
    if (tid == 0) scores[row] = 1.0f / (1.0f + expf(-(red[0] + bp[0])));
}

// ------------- top-1024 of 2048 via radix select ---------------------------
__global__ void topk_radix(const float* __restrict__ scores,
                           float* __restrict__ vals, int* __restrict__ idx)
{
    __shared__ unsigned sv[2048];
    __shared__ int hist[256];
    __shared__ int sh_prefix, sh_remain, sh_wsum[17], sh_out;
    const int tid = threadIdx.x;                 // 1024
    sv[tid] = __float_as_uint(scores[tid]);
    sv[tid + 1024] = __float_as_uint(scores[tid + 1024]);
    if (tid == 0) { sh_prefix = 0; sh_remain = 1024; sh_out = 0; }
    __syncthreads();
    for (int byte = 3; byte >= 0; --byte) {
        if (tid < 256) hist[tid] = 0;
        __syncthreads();
        const unsigned pref = (unsigned)sh_prefix;
        const unsigned pmask = (byte == 3) ? 0u : (0xFFFFFFFFu << ((byte + 1) * 8));
        for (int e = tid; e < 2048; e += 1024) {
            unsigned u = sv[e];
            if ((u & pmask) == (pref & pmask))
                atomicAdd(&hist[(u >> (byte * 8)) & 255], 1);
        }
        __syncthreads();
        if (tid == 0) {
            int rem = sh_remain, b = 255;
            for (; b > 0; --b) {
                if (hist[b] >= rem) break;
                rem -= hist[b];
            }
            sh_prefix = (int)(pref | ((unsigned)b << (byte * 8)));
            sh_remain = rem;
        }
        __syncthreads();
    }
    const unsigned t = (unsigned)sh_prefix;
    const int remain = sh_remain;
    const int wave = tid >> 6, lane = tid & 63;
    int rank[2];
    int base = 0;
    for (int pass = 0; pass < 2; ++pass) {
        const int e = pass * 1024 + tid;
        const bool eq = (sv[e] == t);
        unsigned long long mk = __ballot(eq);
        int wpre = __popcll(mk & ((1ull << lane) - 1ull));
        if (lane == 0) sh_wsum[wave] = __popcll(mk);
        __syncthreads();
        if (tid == 0) {
            int a = base;
            for (int w = 0; w < 16; ++w) { int c = sh_wsum[w]; sh_wsum[w] = a; a += c; }
            sh_wsum[16] = a;
        }
        __syncthreads();
        rank[pass] = eq ? (sh_wsum[wave] + wpre) : 0x7fffffff;
        base = sh_wsum[16];
        __syncthreads();
    }
    for (int pass = 0; pass < 2; ++pass) {
        const int e = pass * 1024 + tid;
        const unsigned u = sv[e];
        const bool sel = (u > t) || (u == t && rank[pass] < remain);
        if (sel) {
            int slot = atomicAdd(&sh_out, 1);
            idx[slot] = e;
            vals[slot] = __uint_as_float(u);
        }
    }
}

// ------------- gather pooled features + build Xtp --------------------------
__global__ void gather_xt(const float* __restrict__ f_g, const int* __restrict__ idx,
                          const float* __restrict__ vals, const float* __restrict__ dinvp,
                          unsigned short* __restrict__ new_hb,
                          unsigned short* __restrict__ xtp)
{
    __shared__ float T[32][33];
    const int tid = threadIdx.x;                 // 256
    const int ploc = tid >> 3, nq = (tid & 7) * 4;
    const int n0 = blockIdx.x * 32;
    const int p = blockIdx.y * 32 + ploc;
    const int s = idx[p];
    const float v = vals[p];
    const float dp = dinvp[p];
    const int srow = (n0 >= 128 ? 2048 : 0) + s;
    float4 f = *(const float4*)(f_g + (size_t)srow * 128 + ((n0 + nq) & 127));
    f.x *= v; f.y *= v; f.z *= v; f.w *= v;
    unsigned short o[4] = { f2bf(f.x), f2bf(f.y), f2bf(f.z), f2bf(f.w) };
    const int hrow = (n0 >= 128 ? 1024 : 0) + p;
    *(ulonglong1*)(new_hb + (size_t)hrow * 128 + ((n0 + nq) & 127)) = *(ulonglong1*)o;
    T[nq + 0][ploc] = f.x * dp; T[nq + 1][ploc] = f.y * dp;
    T[nq + 2][ploc] = f.z * dp; T[nq + 3][ploc] = f.w * dp;
    __syncthreads();
    const int nloc = tid >> 3, pc = (tid & 7) * 4;
    unsigned short o2[4];
#pragma unroll
    for (int c = 0; c < 4; ++c) o2[c] = f2bf(T[nloc][pc + c]);
    *(ulonglong1*)(xtp + (size_t)(n0 + nloc) * 1024 + blockIdx.y * 32 + pc) =
        *(ulonglong1*)o2;
}

// ------------- Ap01 bf16 from packed bits ----------------------------------
__global__ void build_ap(const unsigned long long* __restrict__ bits,
                         const int* __restrict__ idx, unsigned short* __restrict__ Ap)
{
    __shared__ unsigned long long pb[16][32];
    __shared__ unsigned long long qb[16][32];
    const int tp = blockIdx.y * 16;
    const int tq = blockIdx.x * 16;
    const int tid = threadIdx.x;                 // 256
    for (int t = tid; t < 512; t += 256) {
        int r = t >> 5, w = t & 31;
        pb[r][w] = bits[(size_t)idx[tp + r] * 32 + w];
        qb[r][w] = bits[(size_t)idx[tq + r] * 32 + w];
    }
    __syncthreads();
    const int pi = tid >> 4, qi = tid & 15;
    unsigned long long acc = 0;
#pragma unroll
    for (int w = 0; w < 32; ++w) acc |= (pb[pi][w] & qb[qi][w]);
    Ap[(size_t)(tp + pi) * 1024 + tq + qi] = acc ? (unsigned short)0x3F80 : (unsigned short)0;
}

// ------------- rowsum of 0/1 bf16 -> 1/sqrt(deg) ---------------------------
__global__ void rowsum_rsqrt(const unsigned short* __restrict__ Ap,
                             float* __restrict__ dinvp, int n)
{
    const int row = blockIdx.x;
    const int tid = threadIdx.x;                 // 256
    int s = 0;
    for (int j = tid; j < n; j += 256) s += (Ap[(size_t)row * n + j] != 0);
    __shared__ int red[256];
    red[tid] = s;
    __syncthreads();
    for (int st = 128; st > 0; st >>= 1) {
        if (tid < st) red[tid] += red[tid + st];
        __syncthreads();
    }
    if (tid == 0) dinvp[row] = 1.0f / sqrtf((float)red[0]);
}

__global__ void zero_buf(float* __restrict__ p, int n)
{
    const int i = blockIdx.x * 256 + threadIdx.x;
    if (i < n) p[i] = 0.0f;
}

__global__ void zero1(float* __restrict__ p) { p[0] = 0.0f; }

// ---------------------------------------------------------------------------
extern "C" void kernel_launch(void* const* d_in, const int* in_sizes, int n_in,
                              void* d_out, int out_size, void* d_ws, size_t ws_size,
                              hipStream_t stream)
{
    (void)in_sizes; (void)n_in; (void)out_size; (void)ws_size;
    const float* fs      = (const float*)d_in[0];
    const float* ft      = (const float*)d_in[1];
    const float* W_embed = (const float*)d_in[2];
    const float* b_embed = (const float*)d_in[3];
    const float* W_gnn   = (const float*)d_in[4];
    const float* b_gnn   = (const float*)d_in[5];
    const float* W_pool  = (const float*)d_in[6];
    const float* b_pool  = (const float*)d_in[7];
    const float* W_gnnp  = (const float*)d_in[8];
    const float* b_gnnp  = (const float*)d_in[9];
    float* out = (float*)d_out;

    float* ws = (float*)d_ws;
    size_t o = 0;
    auto alloc = [&](size_t n) { float* p = ws + o; o += (n + 3) & ~3ull; return p; };
    float* bigA   = alloc(2048ull * 2048);       // adjacency scores (fp32)
    float* bigB   = alloc(2048ull * 2048);       // partials
    float* f_e    = alloc(4096 * 128);           // fp32 embed (t rows 0.., s rows 2048..)
    float* f_g    = alloc(4096 * 128);           // fp32 f_gt/f_gs
    unsigned short* A01  = (unsigned short*)alloc(2048ull * 2048 / 2);
    unsigned short* febT = (unsigned short*)alloc(3ull * 4096 * 128 / 2); // feb,h1b,h2b
    unsigned short* Xt1  = (unsigned short*)alloc(256ull * 2048 / 2);
    unsigned short* Xt2  = (unsigned short*)alloc(256ull * 2048 / 2);
    unsigned short* f_gb = (unsigned short*)alloc(4096ull * 128 / 2);
    unsigned short* Wtall= (unsigned short*)alloc(5ull * 16384 / 2);
    unsigned short* Ap01 = (unsigned short*)alloc(1024ull * 1024 / 2);
    unsigned short* nhb  = (unsigned short*)alloc(2ull * 2048 * 128 / 2); // new_hb,tmpb
    unsigned short* Xtp  = (unsigned short*)alloc(256ull * 1024 / 2);
    unsigned short* f_pb = (unsigned short*)alloc(2048ull * 128 / 2);
    float* dinv   = alloc(2048);
    float* scores = alloc(2048);
    float* vals   = alloc(1024);
    int*   idxb   = (int*)alloc(1024);
    float* dinvp  = alloc(1024);
    unsigned long long* bits = (unsigned long long*)alloc(2048 * 32 * 2);
    float* nceb   = alloc(2048 * 3 + 1024 * 3);  // rs, cs, pos, rsp, csp, posp

    const size_t FSTR = 4096ull * 128;
    const size_t PSTR = 1024ull * 256;
    unsigned short* feb = febT;
    unsigned short* h1b = febT + FSTR;
    unsigned short* h2b = febT + 2 * FSTR;
    unsigned short* Wt  = Wtall;
    unsigned short* WtP = Wtall + 3ull * 16384;
    unsigned short* tmpb = nhb + 2048ull * 128;
    float* partP  = bigB;
    float* partTP = bigB + 8ull * PSTR;
    float* rs  = nceb;
    float* cs  = nceb + 2048;
    float* pos = nceb + 4096;
    float* rsp  = nceb + 6144;
    float* csp  = nceb + 7168;
    float* posp = nceb + 8192;

    zero1<<<1, 1, 0, stream>>>(out);
    zero_buf<<<36, 256, 0, stream>>>(nceb, 2048 * 3 + 1024 * 3);
    convert_w<<<dim3(5, 128), 128, 0, stream>>>(W_gnn, W_gnnp, Wtall);

    // ---- embed (fp32, merged) + l2norm ----
    gemm_embed<<<dim3(2, 64, 4), 256, 0, stream>>>(fs, ft, W_embed, bigB, FSTR);
    combine_norm<<<4096, 128, 0, stream>>>(bigB, 4, FSTR, b_embed, f_e, feb);

    // ---- adjacency: fp32 gram (exact threshold), A01 bf16 + bits + dinv ----
    gram_tri<<<528, 256, 0, stream>>>(f_e, bigA, 2048);
    threshold_pack<<<2048, 256, 0, stream>>>(bigA, A01, bits, dinv);
    make_xt<<<dim3(8, 64), 256, 0, stream>>>(f_e, dinv, Xt1);

    // ---- hop1/hop2 (bf16 MFMA, teacher+student N=256, split-K 8) ----
    mm_bf16<<<dim3(2, 32, 8), 256, 0, stream>>>(A01, 2048, 0, Xt1, 2048, 0,
                                                bigB, 256, FSTR, 256, 256);
    reduce_hop<<<dim3(8, 64), 256, 0, stream>>>(bigB, 8, FSTR, 2048, dinv, h1b, Xt2);
    mm_bf16<<<dim3(2, 32, 8), 256, 0, stream>>>(A01, 2048, 0, Xt2, 2048, 0,
                                                bigB, 256, FSTR, 256, 256);
    reduce_hop<<<dim3(8, 64), 256, 0, stream>>>(bigB, 8, FSTR, 2048, dinv, h2b, nullptr);

    // ---- TAG linear (batched z=3 over hop terms, M=4096) + l2norm ----
    mm_bf16<<<dim3(1, 64, 3), 256, 0, stream>>>(feb, 128, FSTR, Wt, 128, 16384,
                                                bigB, 128, FSTR, 128, 0);
    combine_norm<<<4096, 128, 0, stream>>>(bigB, 3, FSTR, b_gnn, f_g, f_gb);

    // ---- graph NCE: single fused gram (row sums + col sums + diag) ----
    gram_nce<<<dim3(16, 32), 256, 0, stream>>>(f_gb, f_gb + 2048 * 128, rs, cs, pos);
    nce_final<<<8, 256, 0, stream>>>(rs, cs, pos, 2048, 1.0f / 2048.0f, out);

    // ---- pooling ----
    pool_score<<<2048, 128, 0, stream>>>(f_g, W_pool, b_pool, scores);
    topk_radix<<<1, 1024, 0, stream>>>(scores, vals, idxb);
    build_ap<<<dim3(64, 64), 256, 0, stream>>>(bits, idxb, Ap01);
    rowsum_rsqrt<<<1024, 256, 0, stream>>>(Ap01, dinvp, 1024);
    gather_xt<<<dim3(8, 32), 256, 0, stream>>>(f_g, idxb, vals, dinvp, nhb, Xtp);

    // ---- pooled hop (bf16 MFMA, split-K 8) ----
    mm_bf16<<<dim3(2, 16, 8), 256, 0, stream>>>(Ap01, 1024, 0, Xtp, 1024, 0,
                                                partP, 256, PSTR, 128, 128);
    reduce_hop<<<dim3(8, 32), 256, 0, stream>>>(partP, 8, PSTR, 1024, dinvp, tmpb, nullptr);

    // ---- pooled TAG linear (z=2, M=2048) + l2norm (bf16 out only) ----
    mm_bf16<<<dim3(1, 32, 2), 256, 0, stream>>>(nhb, 128, 2048ull * 128, WtP, 128, 16384,
                                                partTP, 128, PSTR, 128, 0);
    combine_norm<<<2048, 128, 0, stream>>>(partTP, 2, PSTR, b_gnnp, nullptr, f_pb);

    // ---- pooled NCE: single fused gram ----
    gram_nce<<<dim3(8, 16), 256, 0, stream>>>(f_pb, f_pb + 1024 * 128, rsp, csp, posp);
    nce_final<<<4, 256, 0, stream>>>(rsp, csp, posp, 1024, 1.0f / 1024.0f, out);
}